// Round 1
// baseline (5967.885 us; speedup 1.0000x reference)
//
#include <hip/hip_runtime.h>

#define N_NODES 50000
#define N_EDGES 800000
#define C_MSG 200

// ---------------------------------------------------------------------------
// Transpose Wm1 [K, 200] -> Wm1T [200, strideK] (zero-padded), so that the
// per-j weight row is contiguous (enables s_load_dwordx16 scalar streaming).
// ---------------------------------------------------------------------------
__global__ void transpose_wm1(const float* __restrict__ W, float* __restrict__ WT,
                              int K, int strideK) {
    int t = blockIdx.x * blockDim.x + threadIdx.x;
    int total = C_MSG * strideK;
    if (t >= total) return;
    int j = t / strideK;
    int k = t - j * strideK;
    WT[t] = (k < K) ? W[k * C_MSG + j] : 0.0f;
}

// ---------------------------------------------------------------------------
// Node term: agg[n][o] = b1[o] + sum_k maybe_relu(x[n][k]) * W1[k][o]
// Writes (initializes) the full agg buffer; edge kernel atomically adds on top.
// ---------------------------------------------------------------------------
template<int CIN, int COUT, bool RELU_IN>
__global__ __launch_bounds__(256) void node_kernel(const float* __restrict__ x,
                                                   const float* __restrict__ W1,
                                                   const float* __restrict__ b1,
                                                   float* __restrict__ agg) {
    int n = blockIdx.x * blockDim.x + threadIdx.x;
    if (n >= N_NODES) return;
    float xv[CIN];
#pragma unroll
    for (int k = 0; k < CIN; ++k) {
        float v = x[n * CIN + k];
        xv[k] = RELU_IN ? fmaxf(v, 0.0f) : v;
    }
    for (int o = 0; o < COUT; ++o) {          // o uniform -> W1 reads scalarize
        float v = b1[o];
#pragma unroll
        for (int k = 0; k < CIN; ++k) v = fmaf(xv[k], W1[k * COUT + o], v);
        agg[n * COUT + o] = v;
    }
}

// ---------------------------------------------------------------------------
// Fused per-edge kernel: gather -> GEMM1(62x200) -> relu -> GEMM2(200x30)
// -> msg = (m*(xi-xj)) @ W2 + b2 -> atomicAdd into agg[dst].
// One thread per edge; tmp[] and m[] live in VGPRs; all weight accesses are
// wave-uniform (j-loop) so they become scalar loads -> pure VALU inner loop.
// N_EDGES % 256 == 0 so no bounds guard (keeps control flow uniform).
// ---------------------------------------------------------------------------
template<int CIN, int COUT, bool RELU_IN, int WSTRIDE>
__global__ __launch_bounds__(256) void edge_kernel(const float* __restrict__ x,
                                                   const int* __restrict__ src,
                                                   const int* __restrict__ dst,
                                                   const float* __restrict__ ew,
                                                   const float* __restrict__ Wm1T,
                                                   const float* __restrict__ bm1,
                                                   const float* __restrict__ Wm2,
                                                   const float* __restrict__ bm2,
                                                   const float* __restrict__ W2,
                                                   const float* __restrict__ b2,
                                                   float* __restrict__ agg) {
    constexpr int TK = 2 * CIN + 2;
    int e = blockIdx.x * 256 + threadIdx.x;
    int s = src[e];
    int d = dst[e];

    float tmp[TK];
#pragma unroll
    for (int k = 0; k < CIN; ++k) {
        float vi = x[d * CIN + k];
        float vj = x[s * CIN + k];
        if (RELU_IN) { vi = fmaxf(vi, 0.0f); vj = fmaxf(vj, 0.0f); }
        tmp[k] = vi;
        tmp[CIN + k] = vj;
    }
    tmp[2 * CIN]     = ew[2 * e];
    tmp[2 * CIN + 1] = ew[2 * e + 1];

    float m[CIN];
#pragma unroll
    for (int i = 0; i < CIN; ++i) m[i] = bm2[i];

    for (int j = 0; j < C_MSG; ++j) {         // j uniform -> weights scalarize
        const float* __restrict__ wrow = Wm1T + j * WSTRIDE;
        float h = bm1[j];
#pragma unroll
        for (int k = 0; k < TK; ++k) h = fmaf(tmp[k], wrow[k], h);
        h = fmaxf(h, 0.0f);
        const float* __restrict__ w2row = Wm2 + j * CIN;
#pragma unroll
        for (int i = 0; i < CIN; ++i) m[i] = fmaf(h, w2row[i], m[i]);
    }

    float md[CIN];
#pragma unroll
    for (int i = 0; i < CIN; ++i) md[i] = m[i] * (tmp[i] - tmp[CIN + i]);

    for (int o = 0; o < COUT; ++o) {          // o uniform -> W2 reads scalarize
        float v = b2[o];
#pragma unroll
        for (int i = 0; i < CIN; ++i) v = fmaf(md[i], W2[i * COUT + o], v);
        atomicAdd(&agg[d * COUT + o], v);
    }
}

// ---------------------------------------------------------------------------
extern "C" void kernel_launch(void* const* d_in, const int* in_sizes, int n_in,
                              void* d_out, int out_size, void* d_ws, size_t ws_size,
                              hipStream_t stream) {
    const float* features = (const float*)d_in[0];
    const int*   edges    = (const int*)d_in[1];   // [2, E] int32
    const float* ew       = (const float*)d_in[2]; // [E, 2]

    // params: suffix d -> indices 3..10, h -> 11..18, o -> 19..26
    const float* W1_d  = (const float*)d_in[3];
    const float* b1_d  = (const float*)d_in[4];
    const float* Wm1_d = (const float*)d_in[5];
    const float* bm1_d = (const float*)d_in[6];
    const float* Wm2_d = (const float*)d_in[7];
    const float* bm2_d = (const float*)d_in[8];
    const float* W2_d  = (const float*)d_in[9];
    const float* b2_d  = (const float*)d_in[10];

    const float* W1_h  = (const float*)d_in[11];
    const float* b1_h  = (const float*)d_in[12];
    const float* Wm1_h = (const float*)d_in[13];
    const float* bm1_h = (const float*)d_in[14];
    const float* Wm2_h = (const float*)d_in[15];
    const float* bm2_h = (const float*)d_in[16];
    const float* W2_h  = (const float*)d_in[17];
    const float* b2_h  = (const float*)d_in[18];

    const float* W1_o  = (const float*)d_in[19];
    const float* b1_o  = (const float*)d_in[20];
    const float* Wm1_o = (const float*)d_in[21];
    const float* bm1_o = (const float*)d_in[22];
    const float* Wm2_o = (const float*)d_in[23];
    const float* bm2_o = (const float*)d_in[24];
    const float* W2_o  = (const float*)d_in[25];
    const float* b2_o  = (const float*)d_in[26];

    const int* src = edges;            // edges[0] = source
    const int* dst = edges + N_EDGES;  // edges[1] = destination

    // workspace layout (floats)
    float* bufA   = (float*)d_ws;            // [N, 30]
    float* bufB   = bufA + N_NODES * 30;     // [N, 30]
    float* Wm1T_d = bufB + N_NODES * 30;     // [200, 4]
    float* Wm1T_h = Wm1T_d + C_MSG * 4;      // [200, 64]
    float* Wm1T_o = Wm1T_h + C_MSG * 64;     // [200, 64]

    // --- prep: transpose Wm1 for scalar streaming (tiny) ---
    transpose_wm1<<<(C_MSG * 4  + 255) / 256, 256, 0, stream>>>(Wm1_d, Wm1T_d, 4,  4);
    transpose_wm1<<<(C_MSG * 64 + 255) / 256, 256, 0, stream>>>(Wm1_h, Wm1T_h, 62, 64);
    transpose_wm1<<<(C_MSG * 64 + 255) / 256, 256, 0, stream>>>(Wm1_o, Wm1T_o, 62, 64);

    dim3 nb((N_NODES + 255) / 256), eb(N_EDGES / 256), tb(256);
    float* out = (float*)d_out;

    // layer d: features [N,1] -> bufA [N,30]  (no relu on input)
    node_kernel<1, 30, false><<<nb, tb, 0, stream>>>(features, W1_d, b1_d, bufA);
    edge_kernel<1, 30, false, 4><<<eb, tb, 0, stream>>>(features, src, dst, ew,
        Wm1T_d, bm1_d, Wm2_d, bm2_d, W2_d, b2_d, bufA);

    // h1: relu(bufA) -> bufB
    node_kernel<30, 30, true><<<nb, tb, 0, stream>>>(bufA, W1_h, b1_h, bufB);
    edge_kernel<30, 30, true, 64><<<eb, tb, 0, stream>>>(bufA, src, dst, ew,
        Wm1T_h, bm1_h, Wm2_h, bm2_h, W2_h, b2_h, bufB);

    // h2: relu(bufB) -> bufA
    node_kernel<30, 30, true><<<nb, tb, 0, stream>>>(bufB, W1_h, b1_h, bufA);
    edge_kernel<30, 30, true, 64><<<eb, tb, 0, stream>>>(bufB, src, dst, ew,
        Wm1T_h, bm1_h, Wm2_h, bm2_h, W2_h, b2_h, bufA);

    // h3: relu(bufA) -> bufB
    node_kernel<30, 30, true><<<nb, tb, 0, stream>>>(bufA, W1_h, b1_h, bufB);
    edge_kernel<30, 30, true, 64><<<eb, tb, 0, stream>>>(bufA, src, dst, ew,
        Wm1T_h, bm1_h, Wm2_h, bm2_h, W2_h, b2_h, bufB);

    // o: relu(bufB) -> d_out [N,1]  (no output relu)
    node_kernel<30, 1, true><<<nb, tb, 0, stream>>>(bufB, W1_o, b1_o, out);
    edge_kernel<30, 1, true, 64><<<eb, tb, 0, stream>>>(bufB, src, dst, ew,
        Wm1T_o, bm1_o, Wm2_o, bm2_o, W2_o, b2_o, out);
}

// Round 2
// 1660.339 us; speedup vs baseline: 3.5944x; 3.5944x over previous
//
#include <hip/hip_runtime.h>

#define N_NODES 50000
#define N_EDGES 800000
#define C_MSG 200

typedef __bf16 bf16;
typedef __attribute__((ext_vector_type(8))) __bf16 bf16x8;
typedef __attribute__((ext_vector_type(4))) float f32x4;

// ===========================================================================
// CSR build (dst is identical for all 5 layers -> build once per call)
// ===========================================================================
__global__ __launch_bounds__(256) void count_kernel(const int* __restrict__ dst,
                                                    int* __restrict__ counts) {
    int e = blockIdx.x * 256 + threadIdx.x;
    if (e < N_EDGES) atomicAdd(&counts[dst[e]], 1);
}

__global__ __launch_bounds__(256) void scan_kernel(const int* __restrict__ counts,
                                                   int* __restrict__ offsets) {
    __shared__ int part[256];
    __shared__ int base[257];
    int t = threadIdx.x;
    const int chunk = (N_NODES + 255) / 256;   // 196
    int lo = t * chunk, hi = lo + chunk;
    if (hi > N_NODES) hi = N_NODES;
    if (lo > N_NODES) lo = N_NODES;
    int s = 0;
    for (int i = lo; i < hi; ++i) s += counts[i];
    part[t] = s;
    __syncthreads();
    if (t == 0) {
        int r = 0;
        for (int i = 0; i < 256; ++i) { base[i] = r; r += part[i]; }
        base[256] = r;
    }
    __syncthreads();
    int off = base[t];
    for (int i = lo; i < hi; ++i) { offsets[i] = off; off += counts[i]; }
    if (t == 255) offsets[N_NODES] = base[256];
}

__global__ __launch_bounds__(256) void scatter_kernel(const int* __restrict__ dst,
                                                      int* __restrict__ cursor,
                                                      int* __restrict__ perm) {
    int e = blockIdx.x * 256 + threadIdx.x;
    if (e < N_EDGES) {
        int p = atomicAdd(&cursor[dst[e]], 1);
        perm[p] = e;
    }
}

// ===========================================================================
// Weight pre-pack into MFMA B-fragment order (16x16x32 bf16):
// B-frag: lane l holds B[k = kt*32 + (l>>4)*8 + i][n = t*16 + (l&15)], i=0..7
// stored contiguously: out[((t*KT + kt)*64 + l)*8 + i]  (16B per lane)
// ===========================================================================
template<int KREAL, int NREAL, int KT, int NT>
__global__ __launch_bounds__(256) void pack_b(const float* __restrict__ W,
                                              bf16* __restrict__ out) {
    int tid = blockIdx.x * 256 + threadIdx.x;
    if (tid >= NT * KT * 64 * 8) return;
    int i = tid & 7, lane = (tid >> 3) & 63, rest = tid >> 9;
    int kt = rest % KT, t = rest / KT;
    int k = kt * 32 + ((lane >> 4) * 8) + i;
    int n = t * 16 + (lane & 15);
    out[tid] = (k < KREAL && n < NREAL) ? (bf16)W[k * NREAL + n] : (bf16)0.f;
}

// Transpose Wm1_d [4,200] -> [200][4] for the small VALU d-layer kernel
__global__ void transpose_wm1(const float* __restrict__ W, float* __restrict__ WT,
                              int K, int strideK) {
    int t = blockIdx.x * blockDim.x + threadIdx.x;
    int total = C_MSG * strideK;
    if (t >= total) return;
    int j = t / strideK;
    int k = t - j * strideK;
    WT[t] = (k < K) ? W[k * C_MSG + j] : 0.0f;
}

// ===========================================================================
// Node term: agg[n][o] = b1[o] + sum_k maybe_relu(x[n][k]) * W1[k][o]
// ===========================================================================
template<int CIN, int COUT, bool RELU_IN>
__global__ __launch_bounds__(256) void node_kernel(const float* __restrict__ x,
                                                   const float* __restrict__ W1,
                                                   const float* __restrict__ b1,
                                                   float* __restrict__ agg) {
    int n = blockIdx.x * blockDim.x + threadIdx.x;
    if (n >= N_NODES) return;
    float xv[CIN];
#pragma unroll
    for (int k = 0; k < CIN; ++k) {
        float v = x[n * CIN + k];
        xv[k] = RELU_IN ? fmaxf(v, 0.0f) : v;
    }
    for (int o = 0; o < COUT; ++o) {
        float v = b1[o];
#pragma unroll
        for (int k = 0; k < CIN; ++k) v = fmaf(xv[k], W1[k * COUT + o], v);
        agg[n * COUT + o] = v;
    }
}

// ===========================================================================
// Layer-d edge kernel (CIN=1): tiny K -> stay on VALU, write msg (no atomics)
// ===========================================================================
__global__ __launch_bounds__(256) void edge_d_kernel(
    const float* __restrict__ x, const int* __restrict__ src, const int* __restrict__ dst,
    const float* __restrict__ ew, const float* __restrict__ Wm1T, const float* __restrict__ bm1,
    const float* __restrict__ Wm2, const float* __restrict__ bm2,
    const float* __restrict__ W2, const float* __restrict__ b2, bf16* __restrict__ msg)
{
    int e = blockIdx.x * 256 + threadIdx.x;
    float xi = x[dst[e]], xj = x[src[e]];
    float t2 = ew[2 * e], t3 = ew[2 * e + 1];
    float m = bm2[0];
    for (int j = 0; j < C_MSG; ++j) {
        const float* __restrict__ wr = Wm1T + j * 4;
        float h = bm1[j];
        h = fmaf(xi, wr[0], h);
        h = fmaf(xj, wr[1], h);
        h = fmaf(t2, wr[2], h);
        h = fmaf(t3, wr[3], h);
        h = fmaxf(h, 0.f);
        m = fmaf(h, Wm2[j], m);
    }
    float md = m * (xi - xj);
    for (int o = 0; o < 30; ++o) msg[e * 30 + o] = (bf16)fmaf(md, W2[o], b2[o]);
}

// ===========================================================================
// MFMA edge kernel (CIN=30). 4 waves/block, each wave owns 16 edges and a
// private LDS slice -> zero __syncthreads. Verified gfx950 16x16x32 bf16
// fragment layouts: A[m=lane&15][k=(lane>>4)*8+j]; B[k=(lane>>4)*8+j][n=lane&15];
// C/D: col=lane&15, row=(lane>>4)*4+reg.
// Pipeline: gather->tmp[16x64] -> GEMM1 (K=64, N=208) -> relu -> h[16x224]
//           -> GEMM2 (K=224, N=32) -> md = m*diff -> GEMM3 (K=32) -> msg.
// Zero-padding invariants (NaN-safety): tmp cols 62-63 = 0; h cols 200-207
// produced as relu(0+0)=0 (B pad), cols 208-231 zero-filled; Wm2B rows>=200
// zero; md cols 30-31 = 0 (zero bias * zero diff); W2B rows>=30 zero.
// ===========================================================================
template<int NT3, int COUT>
__global__ __launch_bounds__(256) void edge_mfma(
    const float* __restrict__ x, const int* __restrict__ src, const int* __restrict__ dst,
    const float* __restrict__ ew,
    const bf16* __restrict__ Wm1B, const float* __restrict__ bm1,
    const bf16* __restrict__ Wm2B, const float* __restrict__ bm2,
    const bf16* __restrict__ W2B,  const float* __restrict__ b2,
    bf16* __restrict__ msg)
{
    // per-wave slice: tmp [16][72] bf16 (2304B) | h [16][232] bf16 (7424B)
    //                 diff [16][32] f32 (2048B) | md [16][40] bf16 (1280B)
    __shared__ __align__(16) char smem_all[4 * 13056];
    const int tid  = threadIdx.x;
    const int w    = tid >> 6;
    const int lane = tid & 63;
    char* base  = smem_all + w * 13056;
    bf16*  tmpp  = (bf16*) (base);
    bf16*  hp    = (bf16*) (base + 2304);
    float* diffp = (float*)(base + 9728);
    bf16*  mdp   = (bf16*) (base + 11776);

    const int ebase = (blockIdx.x * 4 + w) * 16;
    const int col  = lane & 15;
    const int quad = lane >> 4;
    const int row0 = quad * 4;

    // zero h pad cols [208,232)
    for (int i = lane; i < 16 * 24; i += 64) {
        int r = i / 24, c = 208 + (i % 24);
        hp[r * 232 + c] = (bf16)0.f;
    }

    // ---- gather: tmp[r][:] = [relu(xi)(30) | relu(xj)(30) | ew(2) | 0 0] ----
    for (int r = 0; r < 16; ++r) {
        int e = ebase + r;                 // wave-uniform
        int dN = dst[e], sN = src[e];
        float v = 0.f;
        if (lane < 30)      v = x[dN * 30 + lane];
        else if (lane < 60) v = x[sN * 30 + (lane - 30)];
        else if (lane < 62) v = ew[2 * e + (lane - 60)];
        if (lane < 60) v = fmaxf(v, 0.f);  // relu on layer input (always for CIN=30 layers)
        tmpp[r * 72 + lane] = (bf16)v;
        float vo = __shfl(v, lane + 30);
        if (lane < 32) diffp[r * 32 + lane] = (lane < 30) ? (v - vo) : 0.f;
    }

    // ---- GEMM1: tmp[16x64] @ Wm1[64x208] -> relu -> h ----
    bf16x8 a0 = *(const bf16x8*)(tmpp + col * 72 + quad * 8);
    bf16x8 a1 = *(const bf16x8*)(tmpp + col * 72 + 32 + quad * 8);
    for (int t = 0; t < 13; ++t) {
        bf16x8 b0 = *(const bf16x8*)(Wm1B + ((size_t)(t * 2 + 0) * 64 + lane) * 8);
        bf16x8 b1 = *(const bf16x8*)(Wm1B + ((size_t)(t * 2 + 1) * 64 + lane) * 8);
        f32x4 acc = {0.f, 0.f, 0.f, 0.f};
        acc = __builtin_amdgcn_mfma_f32_16x16x32_bf16(a0, b0, acc, 0, 0, 0);
        acc = __builtin_amdgcn_mfma_f32_16x16x32_bf16(a1, b1, acc, 0, 0, 0);
        int n = t * 16 + col;
        float bias = (n < C_MSG) ? bm1[n] : 0.f;
#pragma unroll
        for (int rg = 0; rg < 4; ++rg) {
            float hv = fmaxf(acc[rg] + bias, 0.f);
            hp[(row0 + rg) * 232 + n] = (bf16)hv;
        }
    }

    // ---- GEMM2: h[16x224] @ Wm2[224x32] -> m ; md = m * diff ----
    f32x4 acc2[2];
    acc2[0] = (f32x4){0.f, 0.f, 0.f, 0.f};
    acc2[1] = (f32x4){0.f, 0.f, 0.f, 0.f};
#pragma unroll
    for (int kt = 0; kt < 7; ++kt) {
        bf16x8 a = *(const bf16x8*)(hp + col * 232 + kt * 32 + quad * 8);
        bf16x8 b0 = *(const bf16x8*)(Wm2B + ((size_t)(0 * 7 + kt) * 64 + lane) * 8);
        bf16x8 b1 = *(const bf16x8*)(Wm2B + ((size_t)(1 * 7 + kt) * 64 + lane) * 8);
        acc2[0] = __builtin_amdgcn_mfma_f32_16x16x32_bf16(a, b0, acc2[0], 0, 0, 0);
        acc2[1] = __builtin_amdgcn_mfma_f32_16x16x32_bf16(a, b1, acc2[1], 0, 0, 0);
    }
#pragma unroll
    for (int nt = 0; nt < 2; ++nt) {
        int i = nt * 16 + col;
        float bias = (i < 30) ? bm2[i] : 0.f;
#pragma unroll
        for (int rg = 0; rg < 4; ++rg) {
            float m = acc2[nt][rg] + bias;
            float dv = diffp[(row0 + rg) * 32 + i];
            mdp[(row0 + rg) * 40 + i] = (bf16)(m * dv);
        }
    }

    // ---- GEMM3: md[16x32] @ W2[32 x NT3*16] -> msg ----
    bf16x8 a3 = *(const bf16x8*)(mdp + col * 40 + quad * 8);
#pragma unroll
    for (int nt = 0; nt < NT3; ++nt) {
        bf16x8 b = *(const bf16x8*)(W2B + ((size_t)nt * 64 + lane) * 8);
        f32x4 acc = {0.f, 0.f, 0.f, 0.f};
        acc = __builtin_amdgcn_mfma_f32_16x16x32_bf16(a3, b, acc, 0, 0, 0);
        int o = nt * 16 + col;
        if (o < COUT) {
            float bias = b2[o];
#pragma unroll
            for (int rg = 0; rg < 4; ++rg) {
                int e = ebase + row0 + rg;
                msg[(size_t)e * COUT + o] = (bf16)(acc[rg] + bias);
            }
        }
    }
}

// ===========================================================================
// Aggregation: out[n][:] += sum over CSR range of msg rows. Half-wave per node.
// ===========================================================================
template<int COUT>
__global__ __launch_bounds__(256) void agg_kernel(const bf16* __restrict__ msg,
                                                  const int* __restrict__ offsets,
                                                  const int* __restrict__ perm,
                                                  float* __restrict__ out) {
    int gh = (blockIdx.x * 256 + threadIdx.x) >> 5;   // node id
    int lane = threadIdx.x & 31;
    if (gh >= N_NODES) return;
    int s0 = offsets[gh], s1 = offsets[gh + 1];
    if (COUT == 30) {
        float v = 0.f;
        for (int j = s0; j < s1; ++j) {
            int e = perm[j];                          // broadcast load
            if (lane < 30) v += (float)msg[(size_t)e * 30 + lane];
        }
        if (lane < 30) out[(size_t)gh * 30 + lane] += v;
    } else {
        float v = 0.f;
        for (int j = s0 + lane; j < s1; j += 32) v += (float)msg[perm[j]];
#pragma unroll
        for (int o = 16; o > 0; o >>= 1) v += __shfl_xor(v, o);
        if (lane == 0) out[gh] += v;
    }
}

// ===========================================================================
extern "C" void kernel_launch(void* const* d_in, const int* in_sizes, int n_in,
                              void* d_out, int out_size, void* d_ws, size_t ws_size,
                              hipStream_t stream) {
    const float* features = (const float*)d_in[0];
    const int*   edges    = (const int*)d_in[1];
    const float* ew       = (const float*)d_in[2];

    const float* W1_d  = (const float*)d_in[3];
    const float* b1_d  = (const float*)d_in[4];
    const float* Wm1_d = (const float*)d_in[5];
    const float* bm1_d = (const float*)d_in[6];
    const float* Wm2_d = (const float*)d_in[7];
    const float* bm2_d = (const float*)d_in[8];
    const float* W2_d  = (const float*)d_in[9];
    const float* b2_d  = (const float*)d_in[10];

    const float* W1_h  = (const float*)d_in[11];
    const float* b1_h  = (const float*)d_in[12];
    const float* Wm1_h = (const float*)d_in[13];
    const float* bm1_h = (const float*)d_in[14];
    const float* Wm2_h = (const float*)d_in[15];
    const float* bm2_h = (const float*)d_in[16];
    const float* W2_h  = (const float*)d_in[17];
    const float* b2_h  = (const float*)d_in[18];

    const float* W1_o  = (const float*)d_in[19];
    const float* b1_o  = (const float*)d_in[20];
    const float* Wm1_o = (const float*)d_in[21];
    const float* bm1_o = (const float*)d_in[22];
    const float* Wm2_o = (const float*)d_in[23];
    const float* bm2_o = (const float*)d_in[24];
    const float* W2_o  = (const float*)d_in[25];
    const float* b2_o  = (const float*)d_in[26];

    const int* src = edges;
    const int* dst = edges + N_EDGES;
    float* out = (float*)d_out;

    // ---- workspace carve-up (64B aligned) ----
    char* p = (char*)d_ws;
    auto alloc = [&](size_t bytes) { char* r = p; p += (bytes + 63) & ~(size_t)63; return r; };
    float* bufA    = (float*)alloc((size_t)N_NODES * 30 * 4);
    float* bufB    = (float*)alloc((size_t)N_NODES * 30 * 4);
    bf16*  msg     = (bf16*) alloc((size_t)N_EDGES * 30 * 2);
    int*   counts  = (int*)  alloc((size_t)N_NODES * 4);
    int*   offsets = (int*)  alloc((size_t)(N_NODES + 1) * 4);
    int*   cursor  = (int*)  alloc((size_t)N_NODES * 4);
    int*   perm    = (int*)  alloc((size_t)N_EDGES * 4);
    float* Wm1T_d  = (float*)alloc((size_t)C_MSG * 4 * 4);
    bf16*  Wm1B_h  = (bf16*) alloc((size_t)13 * 2 * 64 * 8 * 2);
    bf16*  Wm1B_o  = (bf16*) alloc((size_t)13 * 2 * 64 * 8 * 2);
    bf16*  Wm2B_h  = (bf16*) alloc((size_t)2 * 7 * 64 * 8 * 2);
    bf16*  Wm2B_o  = (bf16*) alloc((size_t)2 * 7 * 64 * 8 * 2);
    bf16*  W2B_h   = (bf16*) alloc((size_t)2 * 1 * 64 * 8 * 2);
    bf16*  W2B_o   = (bf16*) alloc((size_t)1 * 1 * 64 * 8 * 2);

    // ---- CSR build (once; dst shared by all layers) ----
    hipMemsetAsync(counts, 0, (size_t)N_NODES * 4, stream);
    count_kernel<<<N_EDGES / 256, 256, 0, stream>>>(dst, counts);
    scan_kernel<<<1, 256, 0, stream>>>(counts, offsets);
    hipMemcpyAsync(cursor, offsets, (size_t)N_NODES * 4, hipMemcpyDeviceToDevice, stream);
    scatter_kernel<<<N_EDGES / 256, 256, 0, stream>>>(dst, cursor, perm);

    // ---- weight packing ----
    transpose_wm1<<<4, 256, 0, stream>>>(Wm1_d, Wm1T_d, 4, 4);
    pack_b<62, 200, 2, 13><<<52, 256, 0, stream>>>(Wm1_h, Wm1B_h);
    pack_b<62, 200, 2, 13><<<52, 256, 0, stream>>>(Wm1_o, Wm1B_o);
    pack_b<200, 30, 7, 2><<<28, 256, 0, stream>>>(Wm2_h, Wm2B_h);
    pack_b<200, 30, 7, 2><<<28, 256, 0, stream>>>(Wm2_o, Wm2B_o);
    pack_b<30, 30, 1, 2><<<4, 256, 0, stream>>>(W2_h, W2B_h);
    pack_b<30, 1, 1, 1><<<2, 256, 0, stream>>>(W2_o, W2B_o);

    dim3 nb((N_NODES + 255) / 256), tb(256);
    dim3 eb_mfma(N_EDGES / 64);       // 4 waves x 16 edges per block
    dim3 eb_valu(N_EDGES / 256);
    dim3 ab(N_NODES * 32 / 256);      // half-wave per node, exact

    // ---- layer d: features [N,1] -> bufA ----
    node_kernel<1, 30, false><<<nb, tb, 0, stream>>>(features, W1_d, b1_d, bufA);
    edge_d_kernel<<<eb_valu, tb, 0, stream>>>(features, src, dst, ew,
        Wm1T_d, bm1_d, Wm2_d, bm2_d, W2_d, b2_d, msg);
    agg_kernel<30><<<ab, tb, 0, stream>>>(msg, offsets, perm, bufA);

    // ---- h1: bufA -> bufB ----
    node_kernel<30, 30, true><<<nb, tb, 0, stream>>>(bufA, W1_h, b1_h, bufB);
    edge_mfma<2, 30><<<eb_mfma, tb, 0, stream>>>(bufA, src, dst, ew,
        Wm1B_h, bm1_h, Wm2B_h, bm2_h, W2B_h, b2_h, msg);
    agg_kernel<30><<<ab, tb, 0, stream>>>(msg, offsets, perm, bufB);

    // ---- h2: bufB -> bufA ----
    node_kernel<30, 30, true><<<nb, tb, 0, stream>>>(bufB, W1_h, b1_h, bufA);
    edge_mfma<2, 30><<<eb_mfma, tb, 0, stream>>>(bufB, src, dst, ew,
        Wm1B_h, bm1_h, Wm2B_h, bm2_h, W2B_h, b2_h, msg);
    agg_kernel<30><<<ab, tb, 0, stream>>>(msg, offsets, perm, bufA);

    // ---- h3: bufA -> bufB ----
    node_kernel<30, 30, true><<<nb, tb, 0, stream>>>(bufA, W1_h, b1_h, bufB);
    edge_mfma<2, 30><<<eb_mfma, tb, 0, stream>>>(bufA, src, dst, ew,
        Wm1B_h, bm1_h, Wm2B_h, bm2_h, W2B_h, b2_h, msg);
    agg_kernel<30><<<ab, tb, 0, stream>>>(msg, offsets, perm, bufB);

    // ---- output: bufB -> out [N,1] ----
    node_kernel<30, 1, true><<<nb, tb, 0, stream>>>(bufB, W1_o, b1_o, out);
    edge_mfma<1, 1><<<eb_mfma, tb, 0, stream>>>(bufB, src, dst, ew,
        Wm1B_o, bm1_o, Wm2B_o, bm2_o, W2B_o, b2_o, msg);
    agg_kernel<1><<<ab, tb, 0, stream>>>(msg, offsets, perm, out);
}

// Round 4
// 978.855 us; speedup vs baseline: 6.0968x; 1.6962x over previous
//
#include <hip/hip_runtime.h>

#define N_NODES 50000
#define N_EDGES 800000
#define C_MSG 200

typedef __bf16 bf16;
typedef __attribute__((ext_vector_type(8))) __bf16 bf16x8;
typedef __attribute__((ext_vector_type(4))) float f32x4;

// ===========================================================================
// CSR build (dst identical for all 5 layers -> once per call)
// ===========================================================================
__global__ __launch_bounds__(256) void count_kernel(const int* __restrict__ dst,
                                                    int* __restrict__ counts) {
    int e = blockIdx.x * 256 + threadIdx.x;
    if (e < N_EDGES) atomicAdd(&counts[dst[e]], 1);
}

__global__ __launch_bounds__(256) void scan_kernel(const int* __restrict__ counts,
                                                   int* __restrict__ offsets) {
    __shared__ int part[256];
    __shared__ int base[257];
    int t = threadIdx.x;
    const int chunk = (N_NODES + 255) / 256;
    int lo = t * chunk, hi = lo + chunk;
    if (hi > N_NODES) hi = N_NODES;
    if (lo > N_NODES) lo = N_NODES;
    int s = 0;
    for (int i = lo; i < hi; ++i) s += counts[i];
    part[t] = s;
    __syncthreads();
    if (t == 0) {
        int r = 0;
        for (int i = 0; i < 256; ++i) { base[i] = r; r += part[i]; }
        base[256] = r;
    }
    __syncthreads();
    int off = base[t];
    for (int i = lo; i < hi; ++i) { offsets[i] = off; off += counts[i]; }
    if (t == 255) offsets[N_NODES] = base[256];
}

__global__ __launch_bounds__(256) void scatter_kernel(const int* __restrict__ dst,
                                                      int* __restrict__ cursor,
                                                      int* __restrict__ perm) {
    int e = blockIdx.x * 256 + threadIdx.x;
    if (e < N_EDGES) {
        int p = atomicAdd(&cursor[dst[e]], 1);
        perm[p] = e;
    }
}

// src_perm/dst_perm/ew(bf16 pair) in perm order — once per call
__global__ __launch_bounds__(256) void build_aux(const int* __restrict__ src,
                                                 const int* __restrict__ dst,
                                                 const float* __restrict__ ew,
                                                 const int* __restrict__ perm,
                                                 int* __restrict__ srcp,
                                                 int* __restrict__ dstp,
                                                 unsigned int* __restrict__ ewbf) {
    int t = blockIdx.x * 256 + threadIdx.x;
    if (t >= N_EDGES) return;
    int p = perm[t];
    srcp[t] = src[p];
    dstp[t] = dst[p];
    union { bf16 b[2]; unsigned int u; } cv;
    cv.b[0] = (bf16)ew[2 * p];
    cv.b[1] = (bf16)ew[2 * p + 1];
    ewbf[t] = cv.u;
}

// ===========================================================================
// Weight packers -> MFMA B-fragment order (16x16x32 bf16). Bias rows ZERO
// (biases added in fp32 epilogues — precision).
// B-frag: lane l holds B[k=kt*32+(l>>4)*8+i][n=t*16+(l&15)], i=0..7,
// stored out[((t*KT+kt)*64+l)*8+i].
// ===========================================================================
// Wm1: tmp col layout = [xi(0..29) | 1 | 0 | xj(32..61) | ew(62,63)]
__global__ __launch_bounds__(256) void pack_wm1(const float* __restrict__ W,
                                                bf16* __restrict__ out) {
    int tid = blockIdx.x * 256 + threadIdx.x;   // 13*2*512 = 13312
    if (tid >= 13 * 2 * 512) return;
    int i = tid & 7, lane = (tid >> 3) & 63, rest = tid >> 9;
    int kt = rest % 2, t = rest / 2;
    int k = kt * 32 + ((lane >> 4) * 8) + i;
    int n = t * 16 + (lane & 15);
    float v = 0.f;
    if (n < C_MSG) {
        if (k < 30)       v = W[k * C_MSG + n];
        else if (k >= 32) v = W[(k - 2) * C_MSG + n];   // 32..63 -> rows 30..61
        // k == 30, 31 -> 0 (tmp cols 30/31 are the 1/0 slots; no bias fold)
    }
    out[tid] = (bf16)v;
}

// Wm2 [200,30]; K=224 (7 tiles), N=32 (2 tiles); rows >=200 zero
__global__ __launch_bounds__(256) void pack_wm2(const float* __restrict__ W,
                                                bf16* __restrict__ out) {
    int tid = blockIdx.x * 256 + threadIdx.x;   // 2*7*512 = 7168
    if (tid >= 2 * 7 * 512) return;
    int i = tid & 7, lane = (tid >> 3) & 63, rest = tid >> 9;
    int kt = rest % 7, t = rest / 7;
    int k = kt * 32 + ((lane >> 4) * 8) + i;
    int n = t * 16 + (lane & 15);
    float v = 0.f;
    if (n < 30 && k < C_MSG) v = W[k * 30 + n];
    out[tid] = (bf16)v;
}

// W2 [30,COUT]; K=32 (1 tile), N = NT*16; rows >=30 zero
template<int COUT, int NT>
__global__ __launch_bounds__(256) void pack_w2(const float* __restrict__ W,
                                               bf16* __restrict__ out) {
    int tid = blockIdx.x * 256 + threadIdx.x;   // NT*512
    if (tid >= NT * 512) return;
    int i = tid & 7, lane = (tid >> 3) & 63, t = tid >> 9;
    int k = ((lane >> 4) * 8) + i;
    int n = t * 16 + (lane & 15);
    float v = 0.f;
    if (n < COUT && k < 30) v = W[k * COUT + n];
    out[tid] = (bf16)v;
}

// x [N,30] f32 -> xbf [N,32] hi (relu'd, col30=1, col31=0)
//             -> xlo [N,32] bf16 residual (x - hi); cols 30,31 = 0
__global__ __launch_bounds__(256) void x_pack(const float* __restrict__ x,
                                              bf16* __restrict__ xbf,
                                              bf16* __restrict__ xlo) {
    int t = blockIdx.x * 256 + threadIdx.x;
    if (t >= N_NODES * 32) return;
    int n = t >> 5, c = t & 31;
    float v = (c < 30) ? fmaxf(x[n * 30 + c], 0.f) : ((c == 30) ? 1.f : 0.f);
    bf16 hi = (bf16)v;
    xbf[t] = hi;
    xlo[t] = (c < 30) ? (bf16)(v - (float)hi) : (bf16)0.f;
}

// ===========================================================================
// Node term: agg[n][o] = b1[o] + sum_k maybe_relu(x[n][k]) * W1[k][o]
// ===========================================================================
template<int CIN, int COUT, bool RELU_IN>
__global__ __launch_bounds__(256) void node_kernel(const float* __restrict__ x,
                                                   const float* __restrict__ W1,
                                                   const float* __restrict__ b1,
                                                   float* __restrict__ agg) {
    int n = blockIdx.x * blockDim.x + threadIdx.x;
    if (n >= N_NODES) return;
    float xv[CIN];
#pragma unroll
    for (int k = 0; k < CIN; ++k) {
        float v = x[n * CIN + k];
        xv[k] = RELU_IN ? fmaxf(v, 0.0f) : v;
    }
    for (int o = 0; o < COUT; ++o) {
        float v = b1[o];
#pragma unroll
        for (int k = 0; k < CIN; ++k) v = fmaf(xv[k], W1[k * COUT + o], v);
        agg[n * COUT + o] = v;
    }
}

// ===========================================================================
// Layer-d edge kernel (CIN=1): VALU path, perm order, msg rows padded to 32
// ===========================================================================
__global__ __launch_bounds__(256) void edge_d_kernel(
    const float* __restrict__ x, const int* __restrict__ dstp, const int* __restrict__ srcp,
    const int* __restrict__ perm, const float* __restrict__ ew,
    const float* __restrict__ Wm1T, const float* __restrict__ bm1,
    const float* __restrict__ Wm2, const float* __restrict__ bm2,
    const float* __restrict__ W2, const float* __restrict__ b2, bf16* __restrict__ msg)
{
    int t = blockIdx.x * 256 + threadIdx.x;
    float xi = x[dstp[t]], xj = x[srcp[t]];
    int p = perm[t];
    float e0 = ew[2 * p], e1 = ew[2 * p + 1];
    float m = bm2[0];
    for (int j = 0; j < C_MSG; ++j) {
        const float* __restrict__ wr = Wm1T + j * 4;
        float h = bm1[j];
        h = fmaf(xi, wr[0], h);
        h = fmaf(xj, wr[1], h);
        h = fmaf(e0, wr[2], h);
        h = fmaf(e1, wr[3], h);
        h = fmaxf(h, 0.f);
        m = fmaf(h, Wm2[j], m);
    }
    float md = m * (xi - xj);
    for (int o = 0; o < 30; ++o) msg[(size_t)t * 32 + o] = (bf16)fmaf(md, W2[o], b2[o]);
}

__global__ void transpose_wm1(const float* __restrict__ W, float* __restrict__ WT) {
    int t = blockIdx.x * blockDim.x + threadIdx.x;
    if (t >= C_MSG * 4) return;
    WT[t] = W[(t & 3) * C_MSG + (t >> 2)];
}

// ===========================================================================
// MFMA edge kernel. 4 waves/block, 16 edges/wave, private LDS slice, no
// __syncthreads. Edges in CSR(perm) order: dst sorted -> xi gather L1-local;
// msg written sequentially for agg.
// Per-wave LDS: tmp[16][72] bf16 (2304) | h[16][232] bf16 (7424) |
//               diff[16][36] f32 (2304) | md[16][40] bf16 (1280) = 13312 B
// -> 53248 B/block -> 3 blocks/CU. All strides give <=2-way bank alias (free).
// diff computed in fp32 from hi+lo bf16 split (error ~2^-18 — cancellation-safe).
// Biases added in fp32 epilogues.
// ===========================================================================
template<int NT3, int COUT>
__global__ __launch_bounds__(256) void edge_mfma(
    const bf16* __restrict__ xbf,          // [N][32] relu'd hi, col30=1, col31=0
    const bf16* __restrict__ xlo,          // [N][32] residual lo, cols>=30 = 0
    const int* __restrict__ dstp, const int* __restrict__ srcp,
    const unsigned int* __restrict__ ewbf, // [E] bf16 pair, perm order
    const bf16* __restrict__ Wm1B, const float* __restrict__ bm1,
    const bf16* __restrict__ Wm2B, const float* __restrict__ bm2,
    const bf16* __restrict__ W2B,  const float* __restrict__ b2,
    bf16* __restrict__ msg)                // [E][32] perm order
{
    __shared__ __align__(16) char smem_all[4 * 13312];
    const int tid = threadIdx.x, w = tid >> 6, lane = tid & 63;
    char* base = smem_all + w * 13312;
    bf16*  tmpp  = (bf16*)base;            // stride 72
    bf16*  hp    = (bf16*)(base + 2304);   // stride 232
    float* diffp = (float*)(base + 9728);  // stride 36
    bf16*  mdp   = (bf16*)(base + 12032);  // stride 40

    const int ebase = (blockIdx.x * 4 + w) * 16;
    const int col = lane & 15, quad = lane >> 4, row0 = quad * 4;

    // init h pad cols [200,226): zeros (bias handled in epilogue)
    for (int i = lane; i < 16 * 26; i += 64) {
        int r = i / 26, c = 200 + i % 26;
        hp[r * 232 + c] = (bf16)0.f;
    }

    // ---- gather: lane -> row r=lane>>2, segment s=lane&3 ----
    {
        int r = lane >> 2, s = lane & 3;
        int dN = dstp[ebase + r];
        int sN = srcp[ebase + r];
        int id = (s < 2) ? dN : sN;
        const bf16* sp = xbf + (size_t)id * 32 + (s & 1) * 16;
        bf16x8 v0 = *(const bf16x8*)sp;
        bf16x8 v1 = *(const bf16x8*)(sp + 8);
        *(bf16x8*)(tmpp + r * 72 + s * 16) = v0;
        *(bf16x8*)(tmpp + r * 72 + s * 16 + 8) = v1;
        // fp32-quality diff for cols s*8 .. s*8+7
        bf16x8 hd = *(const bf16x8*)(xbf + (size_t)dN * 32 + s * 8);
        bf16x8 ld = *(const bf16x8*)(xlo + (size_t)dN * 32 + s * 8);
        bf16x8 hs = *(const bf16x8*)(xbf + (size_t)sN * 32 + s * 8);
        bf16x8 ls = *(const bf16x8*)(xlo + (size_t)sN * 32 + s * 8);
        f32x4 d0, d1;
#pragma unroll
        for (int k = 0; k < 4; ++k)
            d0[k] = ((float)hd[k] + (float)ld[k]) - ((float)hs[k] + (float)ls[k]);
#pragma unroll
        for (int k = 0; k < 4; ++k)
            d1[k] = ((float)hd[k + 4] + (float)ld[k + 4]) - ((float)hs[k + 4] + (float)ls[k + 4]);
        *(f32x4*)(diffp + r * 36 + s * 8) = d0;
        *(f32x4*)(diffp + r * 36 + s * 8 + 4) = d1;
        if (lane < 16) {
            unsigned int e2 = ewbf[ebase + lane];
            *(unsigned int*)(tmpp + lane * 72 + 62) = e2;   // cols 62,63
        }
    }
    // tmp row = [xi(30) | 1 | 0 | xj(30) | ew0 ew1]; diff row = xi-xj (cols>=30: 0)

    // ---- GEMM1: tmp[16x64] @ Wm1B[64x208] -> +bm1, relu -> h ----
    bf16x8 a0 = *(const bf16x8*)(tmpp + col * 72 + quad * 8);
    bf16x8 a1 = *(const bf16x8*)(tmpp + col * 72 + 32 + quad * 8);
#pragma unroll
    for (int t = 0; t < 13; ++t) {
        bf16x8 b0 = *(const bf16x8*)(Wm1B + ((size_t)(t * 2 + 0) * 64 + lane) * 8);
        bf16x8 b1 = *(const bf16x8*)(Wm1B + ((size_t)(t * 2 + 1) * 64 + lane) * 8);
        f32x4 acc = {0.f, 0.f, 0.f, 0.f};
        acc = __builtin_amdgcn_mfma_f32_16x16x32_bf16(a0, b0, acc, 0, 0, 0);
        acc = __builtin_amdgcn_mfma_f32_16x16x32_bf16(a1, b1, acc, 0, 0, 0);
        int n = t * 16 + col;
        if (n < C_MSG) {
            float bias = bm1[n];
#pragma unroll
            for (int rg = 0; rg < 4; ++rg)
                hp[(row0 + rg) * 232 + n] = (bf16)fmaxf(acc[rg] + bias, 0.f);
        }
    }

    // ---- GEMM2: h[16x224] @ Wm2B[224x32] -> +bm2 -> m ; md = m*diff ----
    f32x4 acc2[2];
    acc2[0] = (f32x4){0.f, 0.f, 0.f, 0.f};
    acc2[1] = (f32x4){0.f, 0.f, 0.f, 0.f};
#pragma unroll
    for (int kt = 0; kt < 7; ++kt) {
        bf16x8 a = *(const bf16x8*)(hp + col * 232 + kt * 32 + quad * 8);
        bf16x8 b0 = *(const bf16x8*)(Wm2B + ((size_t)(0 * 7 + kt) * 64 + lane) * 8);
        bf16x8 b1 = *(const bf16x8*)(Wm2B + ((size_t)(1 * 7 + kt) * 64 + lane) * 8);
        acc2[0] = __builtin_amdgcn_mfma_f32_16x16x32_bf16(a, b0, acc2[0], 0, 0, 0);
        acc2[1] = __builtin_amdgcn_mfma_f32_16x16x32_bf16(a, b1, acc2[1], 0, 0, 0);
    }
#pragma unroll
    for (int nt = 0; nt < 2; ++nt) {
        int i = nt * 16 + col;
        float bias = (i < 30) ? bm2[i] : 0.f;
#pragma unroll
        for (int rg = 0; rg < 4; ++rg) {
            int r = row0 + rg;
            float m = acc2[nt][rg] + bias;      // i>=30: acc 0 + 0
            float dv = diffp[r * 36 + i];       // i>=30: 0
            mdp[r * 40 + i] = (bf16)(m * dv);
        }
    }

    // ---- GEMM3: md[16x32] @ W2B[32 x NT3*16] -> +b2 -> msg ----
    bf16x8 a3 = *(const bf16x8*)(mdp + col * 40 + quad * 8);
#pragma unroll
    for (int nt = 0; nt < NT3; ++nt) {
        bf16x8 b = *(const bf16x8*)(W2B + ((size_t)nt * 64 + lane) * 8);
        f32x4 acc = {0.f, 0.f, 0.f, 0.f};
        acc = __builtin_amdgcn_mfma_f32_16x16x32_bf16(a3, b, acc, 0, 0, 0);
        int o = nt * 16 + col;
        if (o < COUT) {
            float bias = b2[o];
#pragma unroll
            for (int rg = 0; rg < 4; ++rg)
                msg[(size_t)(ebase + row0 + rg) * 32 + o] = (bf16)(acc[rg] + bias);
        }
    }
}

// ===========================================================================
// Aggregation: msg rows are CSR-contiguous -> sequential reads.
// Half-wave (32 lanes) per node.
// ===========================================================================
template<int COUT>
__global__ __launch_bounds__(256) void agg_kernel(const bf16* __restrict__ msg,
                                                  const int* __restrict__ offsets,
                                                  float* __restrict__ out) {
    int gh = (blockIdx.x * 256 + threadIdx.x) >> 5;
    int lane = threadIdx.x & 31;
    if (gh >= N_NODES) return;
    int s0 = offsets[gh], s1 = offsets[gh + 1];
    if (COUT == 30) {
        float v0 = 0.f, v1 = 0.f;
        for (int j = s0; j < s1; ++j) {
            if (lane < 15) {
                union { unsigned int u; bf16 b[2]; } cv;
                cv.u = *(const unsigned int*)(msg + (size_t)j * 32 + lane * 2);
                v0 += (float)cv.b[0];
                v1 += (float)cv.b[1];
            }
        }
        if (lane < 15) {
            out[(size_t)gh * 30 + 2 * lane]     += v0;
            out[(size_t)gh * 30 + 2 * lane + 1] += v1;
        }
    } else {
        float v = 0.f;
        for (int j = s0 + lane; j < s1; j += 32) v += (float)msg[(size_t)j * 32];
#pragma unroll
        for (int o = 16; o > 0; o >>= 1) v += __shfl_xor(v, o);
        if (lane == 0) out[gh] += v;
    }
}

// ===========================================================================
extern "C" void kernel_launch(void* const* d_in, const int* in_sizes, int n_in,
                              void* d_out, int out_size, void* d_ws, size_t ws_size,
                              hipStream_t stream) {
    const float* features = (const float*)d_in[0];
    const int*   edges    = (const int*)d_in[1];
    const float* ew       = (const float*)d_in[2];

    const float* W1_d  = (const float*)d_in[3];
    const float* b1_d  = (const float*)d_in[4];
    const float* Wm1_d = (const float*)d_in[5];
    const float* bm1_d = (const float*)d_in[6];
    const float* Wm2_d = (const float*)d_in[7];
    const float* bm2_d = (const float*)d_in[8];
    const float* W2_d  = (const float*)d_in[9];
    const float* b2_d  = (const float*)d_in[10];

    const float* W1_h  = (const float*)d_in[11];
    const float* b1_h  = (const float*)d_in[12];
    const float* Wm1_h = (const float*)d_in[13];
    const float* bm1_h = (const float*)d_in[14];
    const float* Wm2_h = (const float*)d_in[15];
    const float* bm2_h = (const float*)d_in[16];
    const float* W2_h  = (const float*)d_in[17];
    const float* b2_h  = (const float*)d_in[18];

    const float* W1_o  = (const float*)d_in[19];
    const float* b1_o  = (const float*)d_in[20];
    const float* Wm1_o = (const float*)d_in[21];
    const float* bm1_o = (const float*)d_in[22];
    const float* Wm2_o = (const float*)d_in[23];
    const float* bm2_o = (const float*)d_in[24];
    const float* W2_o  = (const float*)d_in[25];
    const float* b2_o  = (const float*)d_in[26];

    const int* src = edges;
    const int* dst = edges + N_EDGES;
    float* out = (float*)d_out;

    // ---- workspace carve-up ----
    char* p = (char*)d_ws;
    auto alloc = [&](size_t bytes) { char* r = p; p += (bytes + 63) & ~(size_t)63; return r; };
    float*        bufA    = (float*)alloc((size_t)N_NODES * 30 * 4);
    float*        bufB    = (float*)alloc((size_t)N_NODES * 30 * 4);
    bf16*         msg     = (bf16*) alloc((size_t)N_EDGES * 32 * 2);
    bf16*         xbf     = (bf16*) alloc((size_t)N_NODES * 32 * 2);
    bf16*         xlo     = (bf16*) alloc((size_t)N_NODES * 32 * 2);
    int*          counts  = (int*)  alloc((size_t)N_NODES * 4);
    int*          offsets = (int*)  alloc((size_t)(N_NODES + 1) * 4);
    int*          cursor  = (int*)  alloc((size_t)N_NODES * 4);
    int*          perm    = (int*)  alloc((size_t)N_EDGES * 4);
    int*          srcp    = (int*)  alloc((size_t)N_EDGES * 4);
    int*          dstp    = (int*)  alloc((size_t)N_EDGES * 4);
    unsigned int* ewbf    = (unsigned int*)alloc((size_t)N_EDGES * 4);
    float*        Wm1T_d  = (float*)alloc((size_t)C_MSG * 4 * 4);
    bf16*         Wm1B_h  = (bf16*) alloc((size_t)13 * 2 * 512 * 2);
    bf16*         Wm1B_o  = (bf16*) alloc((size_t)13 * 2 * 512 * 2);
    bf16*         Wm2B_h  = (bf16*) alloc((size_t)2 * 7 * 512 * 2);
    bf16*         Wm2B_o  = (bf16*) alloc((size_t)2 * 7 * 512 * 2);
    bf16*         W2B_h   = (bf16*) alloc((size_t)2 * 512 * 2);
    bf16*         W2B_o   = (bf16*) alloc((size_t)1 * 512 * 2);

    // ---- CSR + perm-order auxiliaries (once) ----
    hipMemsetAsync(counts, 0, (size_t)N_NODES * 4, stream);
    count_kernel<<<N_EDGES / 256, 256, 0, stream>>>(dst, counts);
    scan_kernel<<<1, 256, 0, stream>>>(counts, offsets);
    hipMemcpyAsync(cursor, offsets, (size_t)N_NODES * 4, hipMemcpyDeviceToDevice, stream);
    scatter_kernel<<<N_EDGES / 256, 256, 0, stream>>>(dst, cursor, perm);
    build_aux<<<N_EDGES / 256, 256, 0, stream>>>(src, dst, ew, perm, srcp, dstp, ewbf);

    // ---- weight packing ----
    transpose_wm1<<<4, 256, 0, stream>>>(Wm1_d, Wm1T_d);
    pack_wm1<<<52, 256, 0, stream>>>(Wm1_h, Wm1B_h);
    pack_wm1<<<52, 256, 0, stream>>>(Wm1_o, Wm1B_o);
    pack_wm2<<<28, 256, 0, stream>>>(Wm2_h, Wm2B_h);
    pack_wm2<<<28, 256, 0, stream>>>(Wm2_o, Wm2B_o);
    pack_w2<30, 2><<<4, 256, 0, stream>>>(W2_h, W2B_h);
    pack_w2<1, 1><<<2, 256, 0, stream>>>(W2_o, W2B_o);

    dim3 nb((N_NODES + 255) / 256), tb(256);
    dim3 eb_mfma(N_EDGES / 64);
    dim3 eb_valu(N_EDGES / 256);
    dim3 ab(N_NODES * 32 / 256);
    dim3 xb(N_NODES * 32 / 256);

    // ---- layer d ----
    node_kernel<1, 30, false><<<nb, tb, 0, stream>>>(features, W1_d, b1_d, bufA);
    edge_d_kernel<<<eb_valu, tb, 0, stream>>>(features, dstp, srcp, perm, ew,
        Wm1T_d, bm1_d, Wm2_d, bm2_d, W2_d, b2_d, msg);
    agg_kernel<30><<<ab, tb, 0, stream>>>(msg, offsets, bufA);

    // ---- h1 ----
    x_pack<<<xb, tb, 0, stream>>>(bufA, xbf, xlo);
    node_kernel<30, 30, true><<<nb, tb, 0, stream>>>(bufA, W1_h, b1_h, bufB);
    edge_mfma<2, 30><<<eb_mfma, tb, 0, stream>>>(xbf, xlo, dstp, srcp, ewbf,
        Wm1B_h, bm1_h, Wm2B_h, bm2_h, W2B_h, b2_h, msg);
    agg_kernel<30><<<ab, tb, 0, stream>>>(msg, offsets, bufB);

    // ---- h2 ----
    x_pack<<<xb, tb, 0, stream>>>(bufB, xbf, xlo);
    node_kernel<30, 30, true><<<nb, tb, 0, stream>>>(bufB, W1_h, b1_h, bufA);
    edge_mfma<2, 30><<<eb_mfma, tb, 0, stream>>>(xbf, xlo, dstp, srcp, ewbf,
        Wm1B_h, bm1_h, Wm2B_h, bm2_h, W2B_h, b2_h, msg);
    agg_kernel<30><<<ab, tb, 0, stream>>>(msg, offsets, bufA);

    // ---- h3 ----
    x_pack<<<xb, tb, 0, stream>>>(bufA, xbf, xlo);
    node_kernel<30, 30, true><<<nb, tb, 0, stream>>>(bufA, W1_h, b1_h, bufB);
    edge_mfma<2, 30><<<eb_mfma, tb, 0, stream>>>(xbf, xlo, dstp, srcp, ewbf,
        Wm1B_h, bm1_h, Wm2B_h, bm2_h, W2B_h, b2_h, msg);
    agg_kernel<30><<<ab, tb, 0, stream>>>(msg, offsets, bufB);

    // ---- output layer ----
    x_pack<<<xb, tb, 0, stream>>>(bufB, xbf, xlo);
    node_kernel<30, 1, true><<<nb, tb, 0, stream>>>(bufB, W1_o, b1_o, out);
    edge_mfma<1, 1><<<eb_mfma, tb, 0, stream>>>(xbf, xlo, dstp, srcp, ewbf,
        Wm1B_o, bm1_o, Wm2B_o, bm2_o, W2B_o, b2_o, msg);
    agg_kernel<1><<<ab, tb, 0, stream>>>(msg, offsets, out);
}

// Round 5
// 959.327 us; speedup vs baseline: 6.2209x; 1.0204x over previous
//
#include <hip/hip_runtime.h>

#define N_NODES 50000
#define N_EDGES 800000
#define C_MSG 200

typedef __bf16 bf16;
typedef __attribute__((ext_vector_type(8))) __bf16 bf16x8;
typedef __attribute__((ext_vector_type(4))) float f32x4;

static __device__ __forceinline__ unsigned int pk_bf16(float a, float b) {
    union { bf16 h[2]; unsigned int u; } cv;
    cv.h[0] = (bf16)a; cv.h[1] = (bf16)b;
    return cv.u;
}

// ===========================================================================
// CSR build (dst identical for all 5 layers -> once per call)
// ===========================================================================
__global__ __launch_bounds__(256) void count_kernel(const int* __restrict__ dst,
                                                    int* __restrict__ counts) {
    int e = blockIdx.x * 256 + threadIdx.x;
    if (e < N_EDGES) atomicAdd(&counts[dst[e]], 1);
}

__global__ __launch_bounds__(256) void scan_kernel(const int* __restrict__ counts,
                                                   int* __restrict__ offsets,
                                                   int* __restrict__ cursor) {
    __shared__ int part[256];
    __shared__ int base[257];
    int t = threadIdx.x;
    const int chunk = (N_NODES + 255) / 256;
    int lo = t * chunk, hi = lo + chunk;
    if (hi > N_NODES) hi = N_NODES;
    if (lo > N_NODES) lo = N_NODES;
    int s = 0;
    for (int i = lo; i < hi; ++i) s += counts[i];
    part[t] = s;
    __syncthreads();
    if (t == 0) {
        int r = 0;
        for (int i = 0; i < 256; ++i) { base[i] = r; r += part[i]; }
        base[256] = r;
    }
    __syncthreads();
    int off = base[t];
    for (int i = lo; i < hi; ++i) {
        offsets[i] = off;
        cursor[i] = off;
        off += counts[i];
    }
    if (t == 255) offsets[N_NODES] = base[256];
}

// scatter + perm-order auxiliaries in one pass
__global__ __launch_bounds__(256) void scatter_kernel(
    const int* __restrict__ src, const int* __restrict__ dst,
    const float* __restrict__ ew, int* __restrict__ cursor,
    int* __restrict__ perm, int* __restrict__ srcp, int* __restrict__ dstp,
    unsigned int* __restrict__ ewbf) {
    int e = blockIdx.x * 256 + threadIdx.x;
    if (e < N_EDGES) {
        int d = dst[e];
        int p = atomicAdd(&cursor[d], 1);
        perm[p] = e;
        srcp[p] = src[e];
        dstp[p] = d;
        ewbf[p] = pk_bf16(ew[2 * e], ew[2 * e + 1]);
    }
}

// ===========================================================================
// Weight packers (device fns) -> MFMA B-frag order (16x16x32), biases folded.
// Fragment f stored at out[f*512 + lane*8 + i]; lane holds B[k][n],
// k = kt*32 + (lane>>4)*8 + i.
// Paired N-tiles: tiles (2p,2p+1) cover columns n = p*32 + 2*(lane&15) + parity
// so the two accumulators of a lane hold ADJACENT columns (packed epilogues).
// ===========================================================================
// Wm1: K=64 over tmp cols [xi(0..29)|1|0|xj(32..61)|ew(62,63)]; bm1 at row 30.
// 13 N-tiles (208): t=0..11 paired, t=12 natural (cols 192..207).
static __device__ void dev_pack_wm1(int tid, const float* W, const float* bm1,
                                    bf16* out) {
    int i = tid & 7, lane = (tid >> 3) & 63, rest = tid >> 9;
    int kt = rest % 2, t = rest / 2;
    int k = kt * 32 + ((lane >> 4) * 8) + i;
    int c = lane & 15;
    int n = (t < 12) ? ((t >> 1) * 32 + 2 * c + (t & 1)) : (192 + c);
    float v = 0.f;
    if (n < C_MSG) {
        if (k < 30)       v = W[k * C_MSG + n];
        else if (k == 30) v = bm1[n];
        else if (k >= 32) v = W[(k - 2) * C_MSG + n];
    }
    out[tid] = (bf16)v;
}

// Wm2 [200,30], bm2 at row 200 (h col 200 = 1); K=224, 2 paired N-tiles.
static __device__ void dev_pack_wm2(int tid, const float* W, const float* bm2,
                                    bf16* out) {
    int i = tid & 7, lane = (tid >> 3) & 63, rest = tid >> 9;
    int kt = rest % 7, nt = rest / 7;
    int k = kt * 32 + ((lane >> 4) * 8) + i;
    int n = 2 * (lane & 15) + nt;
    float v = 0.f;
    if (n < 30) {
        if (k < C_MSG)       v = W[k * 30 + n];
        else if (k == C_MSG) v = bm2[n];
    }
    out[tid] = (bf16)v;
}

// W2_h [30,30], b2 at row 30 (md col 30 = 1); K=32, 2 paired N-tiles.
static __device__ void dev_pack_w2h(int tid, const float* W, const float* b2,
                                    bf16* out) {
    int i = tid & 7, lane = (tid >> 3) & 63, nt = tid >> 9;
    int k = ((lane >> 4) * 8) + i;
    int n = 2 * (lane & 15) + nt;
    float v = 0.f;
    if (n < 30) {
        if (k < 30)       v = W[k * 30 + n];
        else if (k == 30) v = b2[n];
    }
    out[tid] = (bf16)v;
}

// W2_o [30,1], b2 at row 30; 1 natural N-tile.
static __device__ void dev_pack_w2o(int tid, const float* W, const float* b2,
                                    bf16* out) {
    int i = tid & 7, lane = (tid >> 3) & 63;
    int k = ((lane >> 4) * 8) + i;
    int n = lane & 15;
    float v = 0.f;
    if (n == 0) {
        if (k < 30)       v = W[k];
        else if (k == 30) v = b2[0];
    }
    out[tid] = (bf16)v;
}

// Selector for diff GEMM: K=128 over tmp cols (hi_d|hi_s|lo_d|lo_s),
// diff col n = 2*(lane&15) + nt; +1 at k=n (kt0), -1 at 32+n (kt1),
// +1 at 64+n (kt2), -1 at 96+n (kt3). Fragment idx f = kt*2+nt.
static __device__ void dev_pack_sel(int tid, bf16* out) {
    int i = tid & 7, lane = (tid >> 3) & 63, f = tid >> 9;
    int kt = f >> 1, nt = f & 1;
    int kloc = ((lane >> 4) * 8) + i;
    int n = 2 * (lane & 15) + nt;
    float v = (kloc == n && n < 30) ? ((kt & 1) ? -1.f : 1.f) : 0.f;
    out[tid] = (bf16)v;
}

// One dispatch for all weight packing
__global__ __launch_bounds__(256) void pack_all(
    const float* __restrict__ Wm1_h, const float* __restrict__ bm1_h,
    const float* __restrict__ Wm1_o, const float* __restrict__ bm1_o,
    const float* __restrict__ Wm2_h, const float* __restrict__ bm2_h,
    const float* __restrict__ Wm2_o, const float* __restrict__ bm2_o,
    const float* __restrict__ W2_h,  const float* __restrict__ b2_h,
    const float* __restrict__ W2_o,  const float* __restrict__ b2_o,
    const float* __restrict__ Wm1_d,
    bf16* __restrict__ Wm1B_h, bf16* __restrict__ Wm1B_o,
    bf16* __restrict__ Wm2B_h, bf16* __restrict__ Wm2B_o,
    bf16* __restrict__ W2B_h,  bf16* __restrict__ W2B_o,
    bf16* __restrict__ SelB,   float* __restrict__ Wm1T_d) {
    int b = blockIdx.x, t = threadIdx.x;
    if (b < 52)       dev_pack_wm1(b * 256 + t, Wm1_h, bm1_h, Wm1B_h);
    else if (b < 104) dev_pack_wm1((b - 52) * 256 + t, Wm1_o, bm1_o, Wm1B_o);
    else if (b < 132) dev_pack_wm2((b - 104) * 256 + t, Wm2_h, bm2_h, Wm2B_h);
    else if (b < 160) dev_pack_wm2((b - 132) * 256 + t, Wm2_o, bm2_o, Wm2B_o);
    else if (b < 164) dev_pack_w2h((b - 160) * 256 + t, W2_h, b2_h, W2B_h);
    else if (b < 166) dev_pack_w2o((b - 164) * 256 + t, W2_o, b2_o, W2B_o);
    else if (b < 182) dev_pack_sel((b - 166) * 256 + t, SelB);
    else {
        int i = (b - 182) * 256 + t;
        if (i < C_MSG * 4) Wm1T_d[i] = Wm1_d[(i & 3) * C_MSG + (i >> 2)];
    }
}

// ===========================================================================
// Node term: agg[n][o] = b1[o] + sum_k maybe_relu(x[n][k]) * W1[k][o]
// ===========================================================================
template<int CIN, int COUT, bool RELU_IN>
__global__ __launch_bounds__(256) void node_kernel(const float* __restrict__ x,
                                                   const float* __restrict__ W1,
                                                   const float* __restrict__ b1,
                                                   float* __restrict__ agg) {
    int n = blockIdx.x * blockDim.x + threadIdx.x;
    if (n >= N_NODES) return;
    float xv[CIN];
#pragma unroll
    for (int k = 0; k < CIN; ++k) {
        float v = x[n * CIN + k];
        xv[k] = RELU_IN ? fmaxf(v, 0.0f) : v;
    }
    for (int o = 0; o < COUT; ++o) {
        float v = b1[o];
#pragma unroll
        for (int k = 0; k < CIN; ++k) v = fmaf(xv[k], W1[k * COUT + o], v);
        agg[n * COUT + o] = v;
    }
}

// ===========================================================================
// Layer-d edge kernel (CIN=1): full-fp32 VALU path, perm order
// ===========================================================================
__global__ __launch_bounds__(256) void edge_d_kernel(
    const float* __restrict__ x, const int* __restrict__ dstp, const int* __restrict__ srcp,
    const int* __restrict__ perm, const float* __restrict__ ew,
    const float* __restrict__ Wm1T, const float* __restrict__ bm1,
    const float* __restrict__ Wm2, const float* __restrict__ bm2,
    const float* __restrict__ W2, const float* __restrict__ b2, bf16* __restrict__ msg)
{
    int t = blockIdx.x * 256 + threadIdx.x;
    float xi = x[dstp[t]], xj = x[srcp[t]];
    int p = perm[t];
    float e0 = ew[2 * p], e1 = ew[2 * p + 1];
    float m = bm2[0];
    for (int j = 0; j < C_MSG; ++j) {
        const float* __restrict__ wr = Wm1T + j * 4;
        float h = bm1[j];
        h = fmaf(xi, wr[0], h);
        h = fmaf(xj, wr[1], h);
        h = fmaf(e0, wr[2], h);
        h = fmaf(e1, wr[3], h);
        h = fmaxf(h, 0.f);
        m = fmaf(h, Wm2[j], m);
    }
    float md = m * (xi - xj);
    for (int o = 0; o < 15; ++o) {
        float f0 = fmaf(md, W2[2 * o], b2[2 * o]);
        float f1 = fmaf(md, W2[2 * o + 1], b2[2 * o + 1]);
        *(unsigned int*)(msg + (size_t)t * 32 + 2 * o) = pk_bf16(f0, f1);
    }
}

// ===========================================================================
// MFMA edge kernel. 4 waves/block, 16 edges/wave, private LDS slice, no
// __syncthreads. Edges in CSR(perm) order (dst sorted -> L1-local gather,
// sequential msg). Per-wave LDS: tmp[16][136] (4352 B) | h[16][232] (7424 B)
// | md[16][40] (1280 B) = 13056 B -> 52224/block -> 3 blocks/CU.
// tmp row: cols 0-63 = hi [xi|1|0|xj|ew], cols 64-127 = lo [lo_d|0|lo_s|0].
// diff computed by an 8-MFMA selector GEMM (exact fp32, lands in C-layout
// regs). Biases folded: bm1 -> Wm1B row30 (tmp col30=1); bm2 -> Wm2B row200
// (h col200=1); b2 -> W2B row30 (md col30=1). Paired N-tiles -> packed b32
// epilogue writes.
// ===========================================================================
template<int NT3, int COUT>
__global__ __launch_bounds__(256) void edge_mfma(
    const bf16* __restrict__ xbf, const bf16* __restrict__ xlo,
    const int* __restrict__ dstp, const int* __restrict__ srcp,
    const unsigned int* __restrict__ ewbf,
    const bf16* __restrict__ Wm1B, const bf16* __restrict__ SelB,
    const bf16* __restrict__ Wm2B, const bf16* __restrict__ W2B,
    bf16* __restrict__ msg)
{
    __shared__ __align__(16) char smem_all[4 * 13056];
    const int tid = threadIdx.x, w = tid >> 6, lane = tid & 63;
    char* base = smem_all + w * 13056;
    bf16* tmpp = (bf16*)base;              // stride 136
    bf16* hp   = (bf16*)(base + 4352);     // stride 232
    bf16* mdp  = (bf16*)(base + 11776);    // stride 40

    const int ebase = (blockIdx.x * 4 + w) * 16;
    const int col = lane & 15, quad = lane >> 4, row0 = quad * 4;

    // h pad cols [200,224): col 200 = 1 (bm2 slot), rest 0
    for (int i = lane; i < 16 * 24; i += 64) {
        int r = i / 24, c = 200 + i % 24;
        hp[r * 232 + c] = (c == 200) ? (bf16)1.f : (bf16)0.f;
    }

    // ---- gather: lane r=lane>>2, s=lane&3: s0 hi_d->0-31, s1 hi_s->32-63,
    //      s2 lo_d->64-95, s3 lo_s->96-127; then ew overwrites cols 62-63 ----
    {
        int r = lane >> 2, s = lane & 3;
        int id = ((s & 1) == 0) ? dstp[ebase + r] : srcp[ebase + r];
        const bf16* sp = (((s >> 1) == 0) ? xbf : xlo) + (size_t)id * 32;
        bf16x8 v0 = *(const bf16x8*)(sp);
        bf16x8 v1 = *(const bf16x8*)(sp + 8);
        bf16x8 v2 = *(const bf16x8*)(sp + 16);
        bf16x8 v3 = *(const bf16x8*)(sp + 24);
        bf16* dp = tmpp + r * 136 + s * 32;
        *(bf16x8*)(dp) = v0;
        *(bf16x8*)(dp + 8) = v1;
        *(bf16x8*)(dp + 16) = v2;
        *(bf16x8*)(dp + 24) = v3;
        if (lane < 16)
            *(unsigned int*)(tmpp + lane * 136 + 62) = ewbf[ebase + lane];
    }

    // ---- A fragments (K-tiles of tmp) ----
    bf16x8 a0 = *(const bf16x8*)(tmpp + col * 136 + quad * 8);
    bf16x8 a1 = *(const bf16x8*)(tmpp + col * 136 + 32 + quad * 8);
    bf16x8 a2 = *(const bf16x8*)(tmpp + col * 136 + 64 + quad * 8);
    bf16x8 a3 = *(const bf16x8*)(tmpp + col * 136 + 96 + quad * 8);

    // ---- diff[16x32] = (hi_d - hi_s) + (lo_d - lo_s) via selector GEMM ----
    f32x4 dc0 = {0.f, 0.f, 0.f, 0.f}, dc1 = {0.f, 0.f, 0.f, 0.f};
    {
        bf16x8 b;
        b = *(const bf16x8*)(SelB + (size_t)0 * 512 + lane * 8);
        dc0 = __builtin_amdgcn_mfma_f32_16x16x32_bf16(a0, b, dc0, 0, 0, 0);
        b = *(const bf16x8*)(SelB + (size_t)1 * 512 + lane * 8);
        dc1 = __builtin_amdgcn_mfma_f32_16x16x32_bf16(a0, b, dc1, 0, 0, 0);
        b = *(const bf16x8*)(SelB + (size_t)2 * 512 + lane * 8);
        dc0 = __builtin_amdgcn_mfma_f32_16x16x32_bf16(a1, b, dc0, 0, 0, 0);
        b = *(const bf16x8*)(SelB + (size_t)3 * 512 + lane * 8);
        dc1 = __builtin_amdgcn_mfma_f32_16x16x32_bf16(a1, b, dc1, 0, 0, 0);
        b = *(const bf16x8*)(SelB + (size_t)4 * 512 + lane * 8);
        dc0 = __builtin_amdgcn_mfma_f32_16x16x32_bf16(a2, b, dc0, 0, 0, 0);
        b = *(const bf16x8*)(SelB + (size_t)5 * 512 + lane * 8);
        dc1 = __builtin_amdgcn_mfma_f32_16x16x32_bf16(a2, b, dc1, 0, 0, 0);
        b = *(const bf16x8*)(SelB + (size_t)6 * 512 + lane * 8);
        dc0 = __builtin_amdgcn_mfma_f32_16x16x32_bf16(a3, b, dc0, 0, 0, 0);
        b = *(const bf16x8*)(SelB + (size_t)7 * 512 + lane * 8);
        dc1 = __builtin_amdgcn_mfma_f32_16x16x32_bf16(a3, b, dc1, 0, 0, 0);
    }

    // ---- GEMM1: tmp[16x64] @ Wm1[64x208] (+bm1 via row30) -> relu -> h ----
#pragma unroll
    for (int p = 0; p < 6; ++p) {
        const bf16* Wf = Wm1B + (size_t)(4 * p) * 512;
        bf16x8 be0 = *(const bf16x8*)(Wf + lane * 8);
        bf16x8 be1 = *(const bf16x8*)(Wf + 512 + lane * 8);
        bf16x8 bo0 = *(const bf16x8*)(Wf + 1024 + lane * 8);
        bf16x8 bo1 = *(const bf16x8*)(Wf + 1536 + lane * 8);
        f32x4 ae = {0.f, 0.f, 0.f, 0.f}, ao = {0.f, 0.f, 0.f, 0.f};
        ae = __builtin_amdgcn_mfma_f32_16x16x32_bf16(a0, be0, ae, 0, 0, 0);
        ae = __builtin_amdgcn_mfma_f32_16x16x32_bf16(a1, be1, ae, 0, 0, 0);
        ao = __builtin_amdgcn_mfma_f32_16x16x32_bf16(a0, bo0, ao, 0, 0, 0);
        ao = __builtin_amdgcn_mfma_f32_16x16x32_bf16(a1, bo1, ao, 0, 0, 0);
#pragma unroll
        for (int rg = 0; rg < 4; ++rg) {
            unsigned int u = pk_bf16(fmaxf(ae[rg], 0.f), fmaxf(ao[rg], 0.f));
            *(unsigned int*)(hp + (row0 + rg) * 232 + p * 32 + 2 * col) = u;
        }
    }
    {   // leftover N-tile t=12: cols 192..207 (only 192..199 real)
        const bf16* Wf = Wm1B + (size_t)24 * 512;
        bf16x8 b0 = *(const bf16x8*)(Wf + lane * 8);
        bf16x8 b1 = *(const bf16x8*)(Wf + 512 + lane * 8);
        f32x4 acc = {0.f, 0.f, 0.f, 0.f};
        acc = __builtin_amdgcn_mfma_f32_16x16x32_bf16(a0, b0, acc, 0, 0, 0);
        acc = __builtin_amdgcn_mfma_f32_16x16x32_bf16(a1, b1, acc, 0, 0, 0);
        if (col < 8) {
#pragma unroll
            for (int rg = 0; rg < 4; ++rg)
                hp[(row0 + rg) * 232 + 192 + col] = (bf16)fmaxf(acc[rg], 0.f);
        }
    }

    // ---- GEMM2: h[16x224] @ Wm2[224x32] (+bm2 via row200) -> m; md=m*diff ----
    f32x4 m0 = {0.f, 0.f, 0.f, 0.f}, m1 = {0.f, 0.f, 0.f, 0.f};
#pragma unroll
    for (int kt = 0; kt < 7; ++kt) {
        bf16x8 a = *(const bf16x8*)(hp + col * 232 + kt * 32 + quad * 8);
        bf16x8 b0 = *(const bf16x8*)(Wm2B + (size_t)kt * 512 + lane * 8);
        bf16x8 b1 = *(const bf16x8*)(Wm2B + (size_t)(7 + kt) * 512 + lane * 8);
        m0 = __builtin_amdgcn_mfma_f32_16x16x32_bf16(a, b0, m0, 0, 0, 0);
        m1 = __builtin_amdgcn_mfma_f32_16x16x32_bf16(a, b1, m1, 0, 0, 0);
    }
#pragma unroll
    for (int rg = 0; rg < 4; ++rg) {
        unsigned int u = (col == 15) ? pk_bf16(1.f, 0.f)
                                     : pk_bf16(m0[rg] * dc0[rg], m1[rg] * dc1[rg]);
        *(unsigned int*)(mdp + (row0 + rg) * 40 + 2 * col) = u;
    }

    // ---- GEMM3: md[16x32] @ W2[32xN] (+b2 via row30) -> msg ----
    bf16x8 am = *(const bf16x8*)(mdp + col * 40 + quad * 8);
    if (COUT == 30) {
        bf16x8 b0 = *(const bf16x8*)(W2B + lane * 8);
        bf16x8 b1 = *(const bf16x8*)(W2B + 512 + lane * 8);
        f32x4 c0 = {0.f, 0.f, 0.f, 0.f}, c1 = {0.f, 0.f, 0.f, 0.f};
        c0 = __builtin_amdgcn_mfma_f32_16x16x32_bf16(am, b0, c0, 0, 0, 0);
        c1 = __builtin_amdgcn_mfma_f32_16x16x32_bf16(am, b1, c1, 0, 0, 0);
#pragma unroll
        for (int rg = 0; rg < 4; ++rg)
            *(unsigned int*)(msg + (size_t)(ebase + row0 + rg) * 32 + 2 * col) =
                pk_bf16(c0[rg], c1[rg]);
    } else {
        bf16x8 b0 = *(const bf16x8*)(W2B + lane * 8);
        f32x4 c0 = {0.f, 0.f, 0.f, 0.f};
        c0 = __builtin_amdgcn_mfma_f32_16x16x32_bf16(am, b0, c0, 0, 0, 0);
        if (col == 0) {
#pragma unroll
            for (int rg = 0; rg < 4; ++rg)
                msg[(size_t)(ebase + row0 + rg) * 32] = (bf16)c0[rg];
        }
    }
}

// ===========================================================================
// Aggregation (+ fused x_pack for the next layer). Half-wave per node.
// buf = node-term (in) -> final layer value (out, fp32). If WX: also emit
// xbf (relu'd hi, col30=1, col31=0) and xlo (residual) for the next edge_mfma.
// ===========================================================================
template<int COUT, bool WX>
__global__ __launch_bounds__(256) void agg_kernel(const bf16* __restrict__ msg,
                                                  const int* __restrict__ offsets,
                                                  float* __restrict__ buf,
                                                  bf16* __restrict__ xbf,
                                                  bf16* __restrict__ xlo) {
    int gh = (blockIdx.x * 256 + threadIdx.x) >> 5;
    int lane = threadIdx.x & 31;
    if (gh >= N_NODES) return;
    int s0 = offsets[gh], s1 = offsets[gh + 1];
    if (COUT == 30) {
        if (lane < 15) {
            float v0 = 0.f, v1 = 0.f;
            for (int j = s0; j < s1; ++j) {
                union { unsigned int u; bf16 b[2]; } cv;
                cv.u = *(const unsigned int*)(msg + (size_t)j * 32 + lane * 2);
                v0 += (float)cv.b[0];
                v1 += (float)cv.b[1];
            }
            float f0 = buf[(size_t)gh * 30 + 2 * lane] + v0;
            float f1 = buf[(size_t)gh * 30 + 2 * lane + 1] + v1;
            buf[(size_t)gh * 30 + 2 * lane] = f0;
            buf[(size_t)gh * 30 + 2 * lane + 1] = f1;
            if (WX) {
                float r0 = fmaxf(f0, 0.f), r1 = fmaxf(f1, 0.f);
                bf16 h0 = (bf16)r0, h1 = (bf16)r1;
                union { bf16 h[2]; unsigned int u; } hi;
                hi.h[0] = h0; hi.h[1] = h1;
                *(unsigned int*)(xbf + (size_t)gh * 32 + 2 * lane) = hi.u;
                *(unsigned int*)(xlo + (size_t)gh * 32 + 2 * lane) =
                    pk_bf16(r0 - (float)h0, r1 - (float)h1);
            }
        } else if (WX && lane == 15) {
            *(unsigned int*)(xbf + (size_t)gh * 32 + 30) = pk_bf16(1.f, 0.f);
            *(unsigned int*)(xlo + (size_t)gh * 32 + 30) = pk_bf16(0.f, 0.f);
        }
    } else {
        float v = 0.f;
        for (int j = s0 + lane; j < s1; j += 32) v += (float)msg[(size_t)j * 32];
#pragma unroll
        for (int o = 16; o > 0; o >>= 1) v += __shfl_xor(v, o);
        if (lane == 0) buf[gh] += v;
    }
}

// ===========================================================================
extern "C" void kernel_launch(void* const* d_in, const int* in_sizes, int n_in,
                              void* d_out, int out_size, void* d_ws, size_t ws_size,
                              hipStream_t stream) {
    const float* features = (const float*)d_in[0];
    const int*   edges    = (const int*)d_in[1];
    const float* ew       = (const float*)d_in[2];

    const float* W1_d  = (const float*)d_in[3];
    const float* b1_d  = (const float*)d_in[4];
    const float* Wm1_d = (const float*)d_in[5];
    const float* bm1_d = (const float*)d_in[6];
    const float* Wm2_d = (const float*)d_in[7];
    const float* bm2_d = (const float*)d_in[8];
    const float* W2_d  = (const float*)d_in[9];
    const float* b2_d  = (const float*)d_in[10];

    const float* W1_h  = (const float*)d_in[11];
    const float* b1_h  = (const float*)d_in[12];
    const float* Wm1_h = (const float*)d_in[13];
    const float* bm1_h = (const float*)d_in[14];
    const float* Wm2_h = (const float*)d_in[15];
    const float* bm2_h = (const float*)d_in[16];
    const float* W2_h  = (const float*)d_in[17];
    const float* b2_h  = (const float*)d_in[18];

    const float* W1_o  = (const float*)d_in[19];
    const float* b1_o  = (const float*)d_in[20];
    const float* Wm1_o = (const float*)d_in[21];
    const float* bm1_o = (const float*)d_in[22];
    const float* Wm2_o = (const float*)d_in[23];
    const float* bm2_o = (const float*)d_in[24];
    const float* W2_o  = (const float*)d_in[25];
    const float* b2_o  = (const float*)d_in[26];

    const int* src = edges;
    const int* dst = edges + N_EDGES;
    float* out = (float*)d_out;

    // ---- workspace carve-up ----
    char* p = (char*)d_ws;
    auto alloc = [&](size_t bytes) { char* r = p; p += (bytes + 63) & ~(size_t)63; return r; };
    float*        bufA    = (float*)alloc((size_t)N_NODES * 30 * 4);
    float*        bufB    = (float*)alloc((size_t)N_NODES * 30 * 4);
    bf16*         msg     = (bf16*) alloc((size_t)N_EDGES * 32 * 2);
    bf16*         xbf     = (bf16*) alloc((size_t)N_NODES * 32 * 2);
    bf16*         xlo     = (bf16*) alloc((size_t)N_NODES * 32 * 2);
    int*          counts  = (int*)  alloc((size_t)N_NODES * 4);
    int*          offsets = (int*)  alloc((size_t)(N_NODES + 1) * 4);
    int*          cursor  = (int*)  alloc((size_t)N_NODES * 4);
    int*          perm    = (int*)  alloc((size_t)N_EDGES * 4);
    int*          srcp    = (int*)  alloc((size_t)N_EDGES * 4);
    int*          dstp    = (int*)  alloc((size_t)N_EDGES * 4);
    unsigned int* ewbf    = (unsigned int*)alloc((size_t)N_EDGES * 4);
    float*        Wm1T_d  = (float*)alloc((size_t)C_MSG * 4 * 4);
    bf16*         Wm1B_h  = (bf16*) alloc((size_t)26 * 512 * 2);
    bf16*         Wm1B_o  = (bf16*) alloc((size_t)26 * 512 * 2);
    bf16*         Wm2B_h  = (bf16*) alloc((size_t)14 * 512 * 2);
    bf16*         Wm2B_o  = (bf16*) alloc((size_t)14 * 512 * 2);
    bf16*         W2B_h   = (bf16*) alloc((size_t)2 * 512 * 2);
    bf16*         W2B_o   = (bf16*) alloc((size_t)1 * 512 * 2);
    bf16*         SelB    = (bf16*) alloc((size_t)8 * 512 * 2);

    // ---- setup: CSR + perm-order aux + weight packing ----
    hipMemsetAsync(counts, 0, (size_t)N_NODES * 4, stream);
    count_kernel<<<N_EDGES / 256, 256, 0, stream>>>(dst, counts);
    scan_kernel<<<1, 256, 0, stream>>>(counts, offsets, cursor);
    scatter_kernel<<<N_EDGES / 256, 256, 0, stream>>>(src, dst, ew, cursor,
                                                      perm, srcp, dstp, ewbf);
    pack_all<<<186, 256, 0, stream>>>(
        Wm1_h, bm1_h, Wm1_o, bm1_o, Wm2_h, bm2_h, Wm2_o, bm2_o,
        W2_h, b2_h, W2_o, b2_o, Wm1_d,
        Wm1B_h, Wm1B_o, Wm2B_h, Wm2B_o, W2B_h, W2B_o, SelB, Wm1T_d);

    dim3 nb((N_NODES + 255) / 256), tb(256);
    dim3 eb_mfma(N_EDGES / 64);
    dim3 eb_valu(N_EDGES / 256);
    dim3 ab(N_NODES * 32 / 256);

    // ---- layer d ----
    node_kernel<1, 30, false><<<nb, tb, 0, stream>>>(features, W1_d, b1_d, bufA);
    edge_d_kernel<<<eb_valu, tb, 0, stream>>>(features, dstp, srcp, perm, ew,
        Wm1T_d, bm1_d, Wm2_d, bm2_d, W2_d, b2_d, msg);
    agg_kernel<30, true><<<ab, tb, 0, stream>>>(msg, offsets, bufA, xbf, xlo);

    // ---- h1 ----
    node_kernel<30, 30, true><<<nb, tb, 0, stream>>>(bufA, W1_h, b1_h, bufB);
    edge_mfma<2, 30><<<eb_mfma, tb, 0, stream>>>(xbf, xlo, dstp, srcp, ewbf,
        Wm1B_h, SelB, Wm2B_h, W2B_h, msg);
    agg_kernel<30, true><<<ab, tb, 0, stream>>>(msg, offsets, bufB, xbf, xlo);

    // ---- h2 ----
    node_kernel<30, 30, true><<<nb, tb, 0, stream>>>(bufB, W1_h, b1_h, bufA);
    edge_mfma<2, 30><<<eb_mfma, tb, 0, stream>>>(xbf, xlo, dstp, srcp, ewbf,
        Wm1B_h, SelB, Wm2B_h, W2B_h, msg);
    agg_kernel<30, true><<<ab, tb, 0, stream>>>(msg, offsets, bufA, xbf, xlo);

    // ---- h3 ----
    node_kernel<30, 30, true><<<nb, tb, 0, stream>>>(bufA, W1_h, b1_h, bufB);
    edge_mfma<2, 30><<<eb_mfma, tb, 0, stream>>>(xbf, xlo, dstp, srcp, ewbf,
        Wm1B_h, SelB, Wm2B_h, W2B_h, msg);
    agg_kernel<30, true><<<ab, tb, 0, stream>>>(msg, offsets, bufB, xbf, xlo);

    // ---- output layer ----
    node_kernel<30, 1, true><<<nb, tb, 0, stream>>>(bufB, W1_o, b1_o, out);
    edge_mfma<1, 1><<<eb_mfma, tb, 0, stream>>>(xbf, xlo, dstp, srcp, ewbf,
        Wm1B_o, SelB, Wm2B_o, W2B_o, msg);
    agg_kernel<1, false><<<ab, tb, 0, stream>>>(msg, offsets, out, nullptr, nullptr);
}

// Round 6
// 862.653 us; speedup vs baseline: 6.9181x; 1.1121x over previous
//
#include <hip/hip_runtime.h>

#define N_NODES 50000
#define N_EDGES 800000
#define C_MSG 200

typedef __bf16 bf16;
typedef __attribute__((ext_vector_type(8))) __bf16 bf16x8;
typedef __attribute__((ext_vector_type(4))) float f32x4;

static __device__ __forceinline__ unsigned int pk_bf16(float a, float b) {
    union { bf16 h[2]; unsigned int u; } cv;
    cv.h[0] = (bf16)a; cv.h[1] = (bf16)b;
    return cv.u;
}

// ===========================================================================
// CSR build (dst identical for all 5 layers -> once per call)
// ===========================================================================
__global__ __launch_bounds__(256) void count_kernel(const int* __restrict__ dst,
                                                    int* __restrict__ counts) {
    int e = blockIdx.x * 256 + threadIdx.x;
    if (e < N_EDGES) atomicAdd(&counts[dst[e]], 1);
}

// Parallel scan: 196 blocks. Block b: base = sum(counts[0..b*256)) via strided
// loads (L2-hot) + block reduce; then 64-lane shfl_up prefix over its 256.
__global__ __launch_bounds__(256) void scan_kernel(const int* __restrict__ counts,
                                                   int* __restrict__ offsets,
                                                   int* __restrict__ cursor) {
    __shared__ int ws[4];
    const int b = blockIdx.x, t = threadIdx.x;
    const int lane = t & 63, wv = t >> 6;
    // ---- base = prefix sum of all earlier blocks ----
    int acc = 0;
    for (int i = t; i < b * 256; i += 256) acc += counts[i];
#pragma unroll
    for (int d = 32; d > 0; d >>= 1) acc += __shfl_xor(acc, d);
    if (lane == 0) ws[wv] = acc;
    __syncthreads();
    int base = ws[0] + ws[1] + ws[2] + ws[3];
    __syncthreads();
    // ---- local exclusive scan of this block's 256 counts ----
    int i = b * 256 + t;
    int v = (i < N_NODES) ? counts[i] : 0;
    int inc = v;
#pragma unroll
    for (int d = 1; d < 64; d <<= 1) {
        int u = __shfl_up(inc, d);
        if (lane >= d) inc += u;
    }
    if (lane == 63) ws[wv] = inc;
    __syncthreads();
    int waveoff = 0;
    for (int k = 0; k < wv; ++k) waveoff += ws[k];
    int excl = base + waveoff + inc - v;
    if (i < N_NODES) { offsets[i] = excl; cursor[i] = excl; }
    if (i == N_NODES - 1) offsets[N_NODES] = excl + v;
}

// scatter + perm-order auxiliaries in one pass
__global__ __launch_bounds__(256) void scatter_kernel(
    const int* __restrict__ src, const int* __restrict__ dst,
    const float* __restrict__ ew, int* __restrict__ cursor,
    int* __restrict__ perm, int* __restrict__ srcp, int* __restrict__ dstp,
    unsigned int* __restrict__ ewbf) {
    int e = blockIdx.x * 256 + threadIdx.x;
    if (e < N_EDGES) {
        int d = dst[e];
        int p = atomicAdd(&cursor[d], 1);
        perm[p] = e;
        srcp[p] = src[e];
        dstp[p] = d;
        ewbf[p] = pk_bf16(ew[2 * e], ew[2 * e + 1]);
    }
}

// ===========================================================================
// Weight packers -> MFMA B-frag order (16x16x32), biases folded.
// Fragment f stored at out[f*512 + lane*8 + i]; lane holds B[k][n],
// k = kt*32 + (lane>>4)*8 + i. Paired N-tiles: tiles (2p,2p+1) cover columns
// n = p*32 + 2*(lane&15) + parity (adjacent-column accumulators).
// ===========================================================================
static __device__ void dev_pack_wm1(int tid, const float* W, const float* bm1,
                                    bf16* out) {
    int i = tid & 7, lane = (tid >> 3) & 63, rest = tid >> 9;
    int kt = rest % 2, t = rest / 2;
    int k = kt * 32 + ((lane >> 4) * 8) + i;
    int c = lane & 15;
    int n = (t < 12) ? ((t >> 1) * 32 + 2 * c + (t & 1)) : (192 + c);
    float v = 0.f;
    if (n < C_MSG) {
        if (k < 30)       v = W[k * C_MSG + n];
        else if (k == 30) v = bm1[n];
        else if (k >= 32) v = W[(k - 2) * C_MSG + n];
    }
    out[tid] = (bf16)v;
}

static __device__ void dev_pack_wm2(int tid, const float* W, const float* bm2,
                                    bf16* out) {
    int i = tid & 7, lane = (tid >> 3) & 63, rest = tid >> 9;
    int kt = rest % 7, nt = rest / 7;
    int k = kt * 32 + ((lane >> 4) * 8) + i;
    int n = 2 * (lane & 15) + nt;
    float v = 0.f;
    if (n < 30) {
        if (k < C_MSG)       v = W[k * 30 + n];
        else if (k == C_MSG) v = bm2[n];
    }
    out[tid] = (bf16)v;
}

static __device__ void dev_pack_w2h(int tid, const float* W, const float* b2,
                                    bf16* out) {
    int i = tid & 7, lane = (tid >> 3) & 63, nt = tid >> 9;
    int k = ((lane >> 4) * 8) + i;
    int n = 2 * (lane & 15) + nt;
    float v = 0.f;
    if (n < 30) {
        if (k < 30)       v = W[k * 30 + n];
        else if (k == 30) v = b2[n];
    }
    out[tid] = (bf16)v;
}

static __device__ void dev_pack_w2o(int tid, const float* W, const float* b2,
                                    bf16* out) {
    int i = tid & 7, lane = (tid >> 3) & 63;
    int k = ((lane >> 4) * 8) + i;
    int n = lane & 15;
    float v = 0.f;
    if (n == 0) {
        if (k < 30)       v = W[k];
        else if (k == 30) v = b2[0];
    }
    out[tid] = (bf16)v;
}

// Selector for diff GEMM over tmp cols (hi_d|hi_s|lo_d|lo_s)
static __device__ void dev_pack_sel(int tid, bf16* out) {
    int i = tid & 7, lane = (tid >> 3) & 63, f = tid >> 9;
    int kt = f >> 1, nt = f & 1;
    int kloc = ((lane >> 4) * 8) + i;
    int n = 2 * (lane & 15) + nt;
    float v = (kloc == n && n < 30) ? ((kt & 1) ? -1.f : 1.f) : 0.f;
    out[tid] = (bf16)v;
}

__global__ __launch_bounds__(256) void pack_all(
    const float* __restrict__ Wm1_h, const float* __restrict__ bm1_h,
    const float* __restrict__ Wm1_o, const float* __restrict__ bm1_o,
    const float* __restrict__ Wm2_h, const float* __restrict__ bm2_h,
    const float* __restrict__ Wm2_o, const float* __restrict__ bm2_o,
    const float* __restrict__ W2_h,  const float* __restrict__ b2_h,
    const float* __restrict__ W2_o,  const float* __restrict__ b2_o,
    const float* __restrict__ Wm1_d,
    bf16* __restrict__ Wm1B_h, bf16* __restrict__ Wm1B_o,
    bf16* __restrict__ Wm2B_h, bf16* __restrict__ Wm2B_o,
    bf16* __restrict__ W2B_h,  bf16* __restrict__ W2B_o,
    bf16* __restrict__ SelB,   float* __restrict__ Wm1T_d) {
    int b = blockIdx.x, t = threadIdx.x;
    if (b < 52)       dev_pack_wm1(b * 256 + t, Wm1_h, bm1_h, Wm1B_h);
    else if (b < 104) dev_pack_wm1((b - 52) * 256 + t, Wm1_o, bm1_o, Wm1B_o);
    else if (b < 132) dev_pack_wm2((b - 104) * 256 + t, Wm2_h, bm2_h, Wm2B_h);
    else if (b < 160) dev_pack_wm2((b - 132) * 256 + t, Wm2_o, bm2_o, Wm2B_o);
    else if (b < 164) dev_pack_w2h((b - 160) * 256 + t, W2_h, b2_h, W2B_h);
    else if (b < 166) dev_pack_w2o((b - 164) * 256 + t, W2_o, b2_o, W2B_o);
    else if (b < 182) dev_pack_sel((b - 166) * 256 + t, SelB);
    else {
        int i = (b - 182) * 256 + t;
        if (i < C_MSG * 4) Wm1T_d[i] = Wm1_d[(i & 3) * C_MSG + (i >> 2)];
    }
}

// ===========================================================================
// Node term for layer d only: agg[n][o] = b1[o] + features[n]*W1[0][o]
// ===========================================================================
template<int CIN, int COUT, bool RELU_IN>
__global__ __launch_bounds__(256) void node_kernel(const float* __restrict__ x,
                                                   const float* __restrict__ W1,
                                                   const float* __restrict__ b1,
                                                   float* __restrict__ agg) {
    int n = blockIdx.x * blockDim.x + threadIdx.x;
    if (n >= N_NODES) return;
    float xv[CIN];
#pragma unroll
    for (int k = 0; k < CIN; ++k) {
        float v = x[n * CIN + k];
        xv[k] = RELU_IN ? fmaxf(v, 0.0f) : v;
    }
    for (int o = 0; o < COUT; ++o) {
        float v = b1[o];
#pragma unroll
        for (int k = 0; k < CIN; ++k) v = fmaf(xv[k], W1[k * COUT + o], v);
        agg[n * COUT + o] = v;
    }
}

// ===========================================================================
// Layer-d edge kernel (CIN=1): full-fp32 VALU path, perm order
// ===========================================================================
__global__ __launch_bounds__(256) void edge_d_kernel(
    const float* __restrict__ x, const int* __restrict__ dstp, const int* __restrict__ srcp,
    const int* __restrict__ perm, const float* __restrict__ ew,
    const float* __restrict__ Wm1T, const float* __restrict__ bm1,
    const float* __restrict__ Wm2, const float* __restrict__ bm2,
    const float* __restrict__ W2, const float* __restrict__ b2, bf16* __restrict__ msg)
{
    int t = blockIdx.x * 256 + threadIdx.x;
    float xi = x[dstp[t]], xj = x[srcp[t]];
    int p = perm[t];
    float e0 = ew[2 * p], e1 = ew[2 * p + 1];
    float m = bm2[0];
    for (int j = 0; j < C_MSG; ++j) {
        const float* __restrict__ wr = Wm1T + j * 4;
        float h = bm1[j];
        h = fmaf(xi, wr[0], h);
        h = fmaf(xj, wr[1], h);
        h = fmaf(e0, wr[2], h);
        h = fmaf(e1, wr[3], h);
        h = fmaxf(h, 0.f);
        m = fmaf(h, Wm2[j], m);
    }
    float md = m * (xi - xj);
    for (int o = 0; o < 15; ++o) {
        float f0 = fmaf(md, W2[2 * o], b2[2 * o]);
        float f1 = fmaf(md, W2[2 * o + 1], b2[2 * o + 1]);
        *(unsigned int*)(msg + (size_t)t * 32 + 2 * o) = pk_bf16(f0, f1);
    }
}

// ===========================================================================
// MFMA edge kernel (unchanged from R5 — stable baseline for clean counters).
// ===========================================================================
template<int NT3, int COUT>
__global__ __launch_bounds__(256) void edge_mfma(
    const bf16* __restrict__ xbf, const bf16* __restrict__ xlo,
    const int* __restrict__ dstp, const int* __restrict__ srcp,
    const unsigned int* __restrict__ ewbf,
    const bf16* __restrict__ Wm1B, const bf16* __restrict__ SelB,
    const bf16* __restrict__ Wm2B, const bf16* __restrict__ W2B,
    bf16* __restrict__ msg)
{
    __shared__ __align__(16) char smem_all[4 * 13056];
    const int tid = threadIdx.x, w = tid >> 6, lane = tid & 63;
    char* base = smem_all + w * 13056;
    bf16* tmpp = (bf16*)base;              // stride 136
    bf16* hp   = (bf16*)(base + 4352);     // stride 232
    bf16* mdp  = (bf16*)(base + 11776);    // stride 40

    const int ebase = (blockIdx.x * 4 + w) * 16;
    const int col = lane & 15, quad = lane >> 4, row0 = quad * 4;

    for (int i = lane; i < 16 * 24; i += 64) {
        int r = i / 24, c = 200 + i % 24;
        hp[r * 232 + c] = (c == 200) ? (bf16)1.f : (bf16)0.f;
    }

    {
        int r = lane >> 2, s = lane & 3;
        int id = ((s & 1) == 0) ? dstp[ebase + r] : srcp[ebase + r];
        const bf16* sp = (((s >> 1) == 0) ? xbf : xlo) + (size_t)id * 32;
        bf16x8 v0 = *(const bf16x8*)(sp);
        bf16x8 v1 = *(const bf16x8*)(sp + 8);
        bf16x8 v2 = *(const bf16x8*)(sp + 16);
        bf16x8 v3 = *(const bf16x8*)(sp + 24);
        bf16* dp = tmpp + r * 136 + s * 32;
        *(bf16x8*)(dp) = v0;
        *(bf16x8*)(dp + 8) = v1;
        *(bf16x8*)(dp + 16) = v2;
        *(bf16x8*)(dp + 24) = v3;
        if (lane < 16)
            *(unsigned int*)(tmpp + lane * 136 + 62) = ewbf[ebase + lane];
    }

    bf16x8 a0 = *(const bf16x8*)(tmpp + col * 136 + quad * 8);
    bf16x8 a1 = *(const bf16x8*)(tmpp + col * 136 + 32 + quad * 8);
    bf16x8 a2 = *(const bf16x8*)(tmpp + col * 136 + 64 + quad * 8);
    bf16x8 a3 = *(const bf16x8*)(tmpp + col * 136 + 96 + quad * 8);

    f32x4 dc0 = {0.f, 0.f, 0.f, 0.f}, dc1 = {0.f, 0.f, 0.f, 0.f};
    {
        bf16x8 b;
        b = *(const bf16x8*)(SelB + (size_t)0 * 512 + lane * 8);
        dc0 = __builtin_amdgcn_mfma_f32_16x16x32_bf16(a0, b, dc0, 0, 0, 0);
        b = *(const bf16x8*)(SelB + (size_t)1 * 512 + lane * 8);
        dc1 = __builtin_amdgcn_mfma_f32_16x16x32_bf16(a0, b, dc1, 0, 0, 0);
        b = *(const bf16x8*)(SelB + (size_t)2 * 512 + lane * 8);
        dc0 = __builtin_amdgcn_mfma_f32_16x16x32_bf16(a1, b, dc0, 0, 0, 0);
        b = *(const bf16x8*)(SelB + (size_t)3 * 512 + lane * 8);
        dc1 = __builtin_amdgcn_mfma_f32_16x16x32_bf16(a1, b, dc1, 0, 0, 0);
        b = *(const bf16x8*)(SelB + (size_t)4 * 512 + lane * 8);
        dc0 = __builtin_amdgcn_mfma_f32_16x16x32_bf16(a2, b, dc0, 0, 0, 0);
        b = *(const bf16x8*)(SelB + (size_t)5 * 512 + lane * 8);
        dc1 = __builtin_amdgcn_mfma_f32_16x16x32_bf16(a2, b, dc1, 0, 0, 0);
        b = *(const bf16x8*)(SelB + (size_t)6 * 512 + lane * 8);
        dc0 = __builtin_amdgcn_mfma_f32_16x16x32_bf16(a3, b, dc0, 0, 0, 0);
        b = *(const bf16x8*)(SelB + (size_t)7 * 512 + lane * 8);
        dc1 = __builtin_amdgcn_mfma_f32_16x16x32_bf16(a3, b, dc1, 0, 0, 0);
    }

#pragma unroll
    for (int p = 0; p < 6; ++p) {
        const bf16* Wf = Wm1B + (size_t)(4 * p) * 512;
        bf16x8 be0 = *(const bf16x8*)(Wf + lane * 8);
        bf16x8 be1 = *(const bf16x8*)(Wf + 512 + lane * 8);
        bf16x8 bo0 = *(const bf16x8*)(Wf + 1024 + lane * 8);
        bf16x8 bo1 = *(const bf16x8*)(Wf + 1536 + lane * 8);
        f32x4 ae = {0.f, 0.f, 0.f, 0.f}, ao = {0.f, 0.f, 0.f, 0.f};
        ae = __builtin_amdgcn_mfma_f32_16x16x32_bf16(a0, be0, ae, 0, 0, 0);
        ae = __builtin_amdgcn_mfma_f32_16x16x32_bf16(a1, be1, ae, 0, 0, 0);
        ao = __builtin_amdgcn_mfma_f32_16x16x32_bf16(a0, bo0, ao, 0, 0, 0);
        ao = __builtin_amdgcn_mfma_f32_16x16x32_bf16(a1, bo1, ao, 0, 0, 0);
#pragma unroll
        for (int rg = 0; rg < 4; ++rg) {
            unsigned int u = pk_bf16(fmaxf(ae[rg], 0.f), fmaxf(ao[rg], 0.f));
            *(unsigned int*)(hp + (row0 + rg) * 232 + p * 32 + 2 * col) = u;
        }
    }
    {
        const bf16* Wf = Wm1B + (size_t)24 * 512;
        bf16x8 b0 = *(const bf16x8*)(Wf + lane * 8);
        bf16x8 b1 = *(const bf16x8*)(Wf + 512 + lane * 8);
        f32x4 acc = {0.f, 0.f, 0.f, 0.f};
        acc = __builtin_amdgcn_mfma_f32_16x16x32_bf16(a0, b0, acc, 0, 0, 0);
        acc = __builtin_amdgcn_mfma_f32_16x16x32_bf16(a1, b1, acc, 0, 0, 0);
        if (col < 8) {
#pragma unroll
            for (int rg = 0; rg < 4; ++rg)
                hp[(row0 + rg) * 232 + 192 + col] = (bf16)fmaxf(acc[rg], 0.f);
        }
    }

    f32x4 m0 = {0.f, 0.f, 0.f, 0.f}, m1 = {0.f, 0.f, 0.f, 0.f};
#pragma unroll
    for (int kt = 0; kt < 7; ++kt) {
        bf16x8 a = *(const bf16x8*)(hp + col * 232 + kt * 32 + quad * 8);
        bf16x8 b0 = *(const bf16x8*)(Wm2B + (size_t)kt * 512 + lane * 8);
        bf16x8 b1 = *(const bf16x8*)(Wm2B + (size_t)(7 + kt) * 512 + lane * 8);
        m0 = __builtin_amdgcn_mfma_f32_16x16x32_bf16(a, b0, m0, 0, 0, 0);
        m1 = __builtin_amdgcn_mfma_f32_16x16x32_bf16(a, b1, m1, 0, 0, 0);
    }
#pragma unroll
    for (int rg = 0; rg < 4; ++rg) {
        unsigned int u = (col == 15) ? pk_bf16(1.f, 0.f)
                                     : pk_bf16(m0[rg] * dc0[rg], m1[rg] * dc1[rg]);
        *(unsigned int*)(mdp + (row0 + rg) * 40 + 2 * col) = u;
    }

    bf16x8 am = *(const bf16x8*)(mdp + col * 40 + quad * 8);
    if (COUT == 30) {
        bf16x8 b0 = *(const bf16x8*)(W2B + lane * 8);
        bf16x8 b1 = *(const bf16x8*)(W2B + 512 + lane * 8);
        f32x4 c0 = {0.f, 0.f, 0.f, 0.f}, c1 = {0.f, 0.f, 0.f, 0.f};
        c0 = __builtin_amdgcn_mfma_f32_16x16x32_bf16(am, b0, c0, 0, 0, 0);
        c1 = __builtin_amdgcn_mfma_f32_16x16x32_bf16(am, b1, c1, 0, 0, 0);
#pragma unroll
        for (int rg = 0; rg < 4; ++rg)
            *(unsigned int*)(msg + (size_t)(ebase + row0 + rg) * 32 + 2 * col) =
                pk_bf16(c0[rg], c1[rg]);
    } else {
        bf16x8 b0 = *(const bf16x8*)(W2B + lane * 8);
        f32x4 c0 = {0.f, 0.f, 0.f, 0.f};
        c0 = __builtin_amdgcn_mfma_f32_16x16x32_bf16(am, b0, c0, 0, 0, 0);
        if (col == 0) {
#pragma unroll
            for (int rg = 0; rg < 4; ++rg)
                msg[(size_t)(ebase + row0 + rg) * 32] = (bf16)c0[rg];
        }
    }
}

// ===========================================================================
// Fused aggregation: f = nodeterm_cur + msgsum (fp32); emit xbf/xlo = hi/lo of
// relu(f); compute NEXT layer's node term relu(f)@W1n+b1n in-register via
// width-32 shuffles (fma order identical to node_kernel -> bit-exact).
// Half-wave (32 lanes) per node.
// ===========================================================================
template<int CNEXT>
__global__ __launch_bounds__(256) void agg_fused(
    const bf16* __restrict__ msg, const int* __restrict__ offsets,
    const float* __restrict__ bufc,      // node term, current layer [N,30]
    const float* __restrict__ W1n, const float* __restrict__ b1n,
    float* __restrict__ bufn,            // node term, next layer [N,CNEXT]
    bf16* __restrict__ xbf, bf16* __restrict__ xlo) {
    int gh = (blockIdx.x * 256 + threadIdx.x) >> 5;
    int lane = threadIdx.x & 31;
    int s0 = offsets[gh], s1 = offsets[gh + 1];
    float r0 = 0.f, r1 = 0.f;
    if (lane < 15) {
        float v0 = 0.f, v1 = 0.f;
        for (int j = s0; j < s1; ++j) {
            union { unsigned int u; bf16 b[2]; } cv;
            cv.u = *(const unsigned int*)(msg + (size_t)j * 32 + lane * 2);
            v0 += (float)cv.b[0];
            v1 += (float)cv.b[1];
        }
        float f0 = bufc[(size_t)gh * 30 + 2 * lane] + v0;
        float f1 = bufc[(size_t)gh * 30 + 2 * lane + 1] + v1;
        r0 = fmaxf(f0, 0.f);
        r1 = fmaxf(f1, 0.f);
        bf16 h0 = (bf16)r0, h1 = (bf16)r1;
        union { bf16 h[2]; unsigned int u; } hi;
        hi.h[0] = h0; hi.h[1] = h1;
        *(unsigned int*)(xbf + (size_t)gh * 32 + 2 * lane) = hi.u;
        *(unsigned int*)(xlo + (size_t)gh * 32 + 2 * lane) =
            pk_bf16(r0 - (float)h0, r1 - (float)h1);
    } else if (lane == 15) {
        *(unsigned int*)(xbf + (size_t)gh * 32 + 30) = pk_bf16(1.f, 0.f);
        *(unsigned int*)(xlo + (size_t)gh * 32 + 30) = 0u;
    }
    // ---- next node term (fma order == node_kernel: k ascending) ----
    if (CNEXT == 30) {
        float acc0 = 0.f, acc1 = 0.f;
        if (lane < 15) { acc0 = b1n[2 * lane]; acc1 = b1n[2 * lane + 1]; }
        for (int k2 = 0; k2 < 15; ++k2) {
            float rk0 = __shfl(r0, k2, 32);
            float rk1 = __shfl(r1, k2, 32);
            if (lane < 15) {
                const float* w0 = W1n + (2 * k2) * 30 + 2 * lane;
                const float* w1 = W1n + (2 * k2 + 1) * 30 + 2 * lane;
                acc0 = fmaf(rk0, w0[0], acc0);
                acc1 = fmaf(rk0, w0[1], acc1);
                acc0 = fmaf(rk1, w1[0], acc0);
                acc1 = fmaf(rk1, w1[1], acc1);
            }
        }
        if (lane < 15) {
            bufn[(size_t)gh * 30 + 2 * lane] = acc0;
            bufn[(size_t)gh * 30 + 2 * lane + 1] = acc1;
        }
    } else {
        float acc = b1n[0];
        for (int k2 = 0; k2 < 15; ++k2) {
            float rk0 = __shfl(r0, k2, 32);
            float rk1 = __shfl(r1, k2, 32);
            acc = fmaf(rk0, W1n[2 * k2], acc);
            acc = fmaf(rk1, W1n[2 * k2 + 1], acc);
        }
        if (lane == 0) bufn[gh] = acc;
    }
}

// Final aggregation for the output layer (msg COUT=1): out[gh] += msgsum
__global__ __launch_bounds__(256) void agg_last(const bf16* __restrict__ msg,
                                                const int* __restrict__ offsets,
                                                float* __restrict__ out) {
    int gh = (blockIdx.x * 256 + threadIdx.x) >> 5;
    int lane = threadIdx.x & 31;
    int s0 = offsets[gh], s1 = offsets[gh + 1];
    float v = 0.f;
    for (int j = s0 + lane; j < s1; j += 32) v += (float)msg[(size_t)j * 32];
#pragma unroll
    for (int o = 16; o > 0; o >>= 1) v += __shfl_xor(v, o);
    if (lane == 0) out[gh] += v;
}

// ===========================================================================
extern "C" void kernel_launch(void* const* d_in, const int* in_sizes, int n_in,
                              void* d_out, int out_size, void* d_ws, size_t ws_size,
                              hipStream_t stream) {
    const float* features = (const float*)d_in[0];
    const int*   edges    = (const int*)d_in[1];
    const float* ew       = (const float*)d_in[2];

    const float* W1_d  = (const float*)d_in[3];
    const float* b1_d  = (const float*)d_in[4];
    const float* Wm1_d = (const float*)d_in[5];
    const float* bm1_d = (const float*)d_in[6];
    const float* Wm2_d = (const float*)d_in[7];
    const float* bm2_d = (const float*)d_in[8];
    const float* W2_d  = (const float*)d_in[9];
    const float* b2_d  = (const float*)d_in[10];

    const float* W1_h  = (const float*)d_in[11];
    const float* b1_h  = (const float*)d_in[12];
    const float* Wm1_h = (const float*)d_in[13];
    const float* bm1_h = (const float*)d_in[14];
    const float* Wm2_h = (const float*)d_in[15];
    const float* bm2_h = (const float*)d_in[16];
    const float* W2_h  = (const float*)d_in[17];
    const float* b2_h  = (const float*)d_in[18];

    const float* W1_o  = (const float*)d_in[19];
    const float* b1_o  = (const float*)d_in[20];
    const float* Wm1_o = (const float*)d_in[21];
    const float* bm1_o = (const float*)d_in[22];
    const float* Wm2_o = (const float*)d_in[23];
    const float* bm2_o = (const float*)d_in[24];
    const float* W2_o  = (const float*)d_in[25];
    const float* b2_o  = (const float*)d_in[26];

    const int* src = edges;
    const int* dst = edges + N_EDGES;
    float* out = (float*)d_out;

    // ---- workspace carve-up ----
    char* p = (char*)d_ws;
    auto alloc = [&](size_t bytes) { char* r = p; p += (bytes + 63) & ~(size_t)63; return r; };
    float*        bufA    = (float*)alloc((size_t)N_NODES * 30 * 4);
    float*        bufB    = (float*)alloc((size_t)N_NODES * 30 * 4);
    bf16*         msg     = (bf16*) alloc((size_t)N_EDGES * 32 * 2);
    bf16*         xbf     = (bf16*) alloc((size_t)N_NODES * 32 * 2);
    bf16*         xlo     = (bf16*) alloc((size_t)N_NODES * 32 * 2);
    int*          counts  = (int*)  alloc((size_t)N_NODES * 4);
    int*          offsets = (int*)  alloc((size_t)(N_NODES + 1) * 4);
    int*          cursor  = (int*)  alloc((size_t)N_NODES * 4);
    int*          perm    = (int*)  alloc((size_t)N_EDGES * 4);
    int*          srcp    = (int*)  alloc((size_t)N_EDGES * 4);
    int*          dstp    = (int*)  alloc((size_t)N_EDGES * 4);
    unsigned int* ewbf    = (unsigned int*)alloc((size_t)N_EDGES * 4);
    float*        Wm1T_d  = (float*)alloc((size_t)C_MSG * 4 * 4);
    bf16*         Wm1B_h  = (bf16*) alloc((size_t)26 * 512 * 2);
    bf16*         Wm1B_o  = (bf16*) alloc((size_t)26 * 512 * 2);
    bf16*         Wm2B_h  = (bf16*) alloc((size_t)14 * 512 * 2);
    bf16*         Wm2B_o  = (bf16*) alloc((size_t)14 * 512 * 2);
    bf16*         W2B_h   = (bf16*) alloc((size_t)2 * 512 * 2);
    bf16*         W2B_o   = (bf16*) alloc((size_t)1 * 512 * 2);
    bf16*         SelB    = (bf16*) alloc((size_t)8 * 512 * 2);

    // ---- setup: CSR + perm-order aux + weight packing ----
    hipMemsetAsync(counts, 0, (size_t)N_NODES * 4, stream);
    count_kernel<<<N_EDGES / 256, 256, 0, stream>>>(dst, counts);
    scan_kernel<<<(N_NODES + 255) / 256, 256, 0, stream>>>(counts, offsets, cursor);
    scatter_kernel<<<N_EDGES / 256, 256, 0, stream>>>(src, dst, ew, cursor,
                                                      perm, srcp, dstp, ewbf);
    pack_all<<<186, 256, 0, stream>>>(
        Wm1_h, bm1_h, Wm1_o, bm1_o, Wm2_h, bm2_h, Wm2_o, bm2_o,
        W2_h, b2_h, W2_o, b2_o, Wm1_d,
        Wm1B_h, Wm1B_o, Wm2B_h, Wm2B_o, W2B_h, W2B_o, SelB, Wm1T_d);

    dim3 nb((N_NODES + 255) / 256), tb(256);
    dim3 eb_mfma(N_EDGES / 64);
    dim3 eb_valu(N_EDGES / 256);
    dim3 ab(N_NODES * 32 / 256);

    // ---- layer d: node term, fp32 edge path, fused agg -> bufB(h1 term) ----
    node_kernel<1, 30, false><<<nb, tb, 0, stream>>>(features, W1_d, b1_d, bufA);
    edge_d_kernel<<<eb_valu, tb, 0, stream>>>(features, dstp, srcp, perm, ew,
        Wm1T_d, bm1_d, Wm2_d, bm2_d, W2_d, b2_d, msg);
    agg_fused<30><<<ab, tb, 0, stream>>>(msg, offsets, bufA, W1_h, b1_h, bufB, xbf, xlo);

    // ---- h1 ----
    edge_mfma<2, 30><<<eb_mfma, tb, 0, stream>>>(xbf, xlo, dstp, srcp, ewbf,
        Wm1B_h, SelB, Wm2B_h, W2B_h, msg);
    agg_fused<30><<<ab, tb, 0, stream>>>(msg, offsets, bufB, W1_h, b1_h, bufA, xbf, xlo);

    // ---- h2 ----
    edge_mfma<2, 30><<<eb_mfma, tb, 0, stream>>>(xbf, xlo, dstp, srcp, ewbf,
        Wm1B_h, SelB, Wm2B_h, W2B_h, msg);
    agg_fused<30><<<ab, tb, 0, stream>>>(msg, offsets, bufA, W1_h, b1_h, bufB, xbf, xlo);

    // ---- h3 (next node term = output layer, CNEXT=1 -> writes d_out) ----
    edge_mfma<2, 30><<<eb_mfma, tb, 0, stream>>>(xbf, xlo, dstp, srcp, ewbf,
        Wm1B_h, SelB, Wm2B_h, W2B_h, msg);
    agg_fused<1><<<ab, tb, 0, stream>>>(msg, offsets, bufB, W1_o, b1_o, out, xbf, xlo);

    // ---- output layer ----
    edge_mfma<1, 1><<<eb_mfma, tb, 0, stream>>>(xbf, xlo, dstp, srcp, ewbf,
        Wm1B_o, SelB, Wm2B_o, W2B_o, msg);
    agg_last<<<ab, tb, 0, stream>>>(msg, offsets, out);
}

// Round 7
// 775.491 us; speedup vs baseline: 7.6956x; 1.1124x over previous
//
#include <hip/hip_runtime.h>

#define N_NODES 50000
#define N_EDGES 800000
#define C_MSG 200

typedef __bf16 bf16;
typedef __attribute__((ext_vector_type(8))) __bf16 bf16x8;
typedef __attribute__((ext_vector_type(4))) float f32x4;

static __device__ __forceinline__ unsigned int pk_bf16(float a, float b) {
    union { bf16 h[2]; unsigned int u; } cv;
    cv.h[0] = (bf16)a; cv.h[1] = (bf16)b;
    return cv.u;
}

// ===========================================================================
// Weight packers (device fns) -> MFMA B-frag order (16x16x32), biases folded.
// Fragment f at out[f*512 + lane*8 + i]; lane holds B[k][n], k=kt*32+(lane>>4)*8+i.
// Paired N-tiles: pair p covers cols p*32 + 2*(lane&15) + parity.
// ===========================================================================
static __device__ void dev_pack_wm1(int tid, const float* W, const float* bm1,
                                    bf16* out) {
    int i = tid & 7, lane = (tid >> 3) & 63, rest = tid >> 9;
    int kt = rest % 2, t = rest / 2;
    int k = kt * 32 + ((lane >> 4) * 8) + i;
    int c = lane & 15;
    int n = (t < 12) ? ((t >> 1) * 32 + 2 * c + (t & 1)) : (192 + c);
    float v = 0.f;
    if (n < C_MSG) {
        if (k < 30)       v = W[k * C_MSG + n];
        else if (k == 30) v = bm1[n];
        else if (k >= 32) v = W[(k - 2) * C_MSG + n];
    }
    out[tid] = (bf16)v;
}

static __device__ void dev_pack_wm2(int tid, const float* W, const float* bm2,
                                    bf16* out) {
    int i = tid & 7, lane = (tid >> 3) & 63, rest = tid >> 9;
    int kt = rest % 7, nt = rest / 7;
    int k = kt * 32 + ((lane >> 4) * 8) + i;
    int n = 2 * (lane & 15) + nt;
    float v = 0.f;
    if (n < 30) {
        if (k < C_MSG)       v = W[k * 30 + n];
        else if (k == C_MSG) v = bm2[n];
    }
    out[tid] = (bf16)v;
}

static __device__ void dev_pack_w2h(int tid, const float* W, const float* b2,
                                    bf16* out) {
    int i = tid & 7, lane = (tid >> 3) & 63, nt = tid >> 9;
    int k = ((lane >> 4) * 8) + i;
    int n = 2 * (lane & 15) + nt;
    float v = 0.f;
    if (n < 30) {
        if (k < 30)       v = W[k * 30 + n];
        else if (k == 30) v = b2[n];
    }
    out[tid] = (bf16)v;
}

static __device__ void dev_pack_w2o(int tid, const float* W, const float* b2,
                                    bf16* out) {
    int i = tid & 7, lane = (tid >> 3) & 63;
    int k = ((lane >> 4) * 8) + i;
    int n = lane & 15;
    float v = 0.f;
    if (n == 0) {
        if (k < 30)       v = W[k];
        else if (k == 30) v = b2[0];
    }
    out[tid] = (bf16)v;
}

static __device__ void dev_pack_sel(int tid, bf16* out) {
    int i = tid & 7, lane = (tid >> 3) & 63, f = tid >> 9;
    int kt = f >> 1, nt = f & 1;
    int kloc = ((lane >> 4) * 8) + i;
    int n = 2 * (lane & 15) + nt;
    float v = (kloc == n && n < 30) ? ((kt & 1) ? -1.f : 1.f) : 0.f;
    out[tid] = (bf16)v;
}

// ===========================================================================
// setup_a: count (3125 blocks) + pack_all (186) + node_d (196) in ONE dispatch
// ===========================================================================
__global__ __launch_bounds__(256) void setup_a(
    const int* __restrict__ dst, int* __restrict__ counts,
    const float* __restrict__ Wm1_h, const float* __restrict__ bm1_h,
    const float* __restrict__ Wm1_o, const float* __restrict__ bm1_o,
    const float* __restrict__ Wm2_h, const float* __restrict__ bm2_h,
    const float* __restrict__ Wm2_o, const float* __restrict__ bm2_o,
    const float* __restrict__ W2_h,  const float* __restrict__ b2_h,
    const float* __restrict__ W2_o,  const float* __restrict__ b2_o,
    const float* __restrict__ Wm1_d,
    bf16* __restrict__ Wm1B_h, bf16* __restrict__ Wm1B_o,
    bf16* __restrict__ Wm2B_h, bf16* __restrict__ Wm2B_o,
    bf16* __restrict__ W2B_h,  bf16* __restrict__ W2B_o,
    bf16* __restrict__ SelB,   float* __restrict__ Wm1T_d,
    const float* __restrict__ features, const float* __restrict__ W1_d,
    const float* __restrict__ b1_d, float* __restrict__ bufA) {
    int b = blockIdx.x, t = threadIdx.x;
    if (b < 3125) {                                  // count
        int e = b * 256 + t;
        if (e < N_EDGES) atomicAdd(&counts[dst[e]], 1);
    } else if (b < 3311) {                           // pack_all
        int pb = b - 3125;
        if (pb < 52)       dev_pack_wm1(pb * 256 + t, Wm1_h, bm1_h, Wm1B_h);
        else if (pb < 104) dev_pack_wm1((pb - 52) * 256 + t, Wm1_o, bm1_o, Wm1B_o);
        else if (pb < 132) dev_pack_wm2((pb - 104) * 256 + t, Wm2_h, bm2_h, Wm2B_h);
        else if (pb < 160) dev_pack_wm2((pb - 132) * 256 + t, Wm2_o, bm2_o, Wm2B_o);
        else if (pb < 164) dev_pack_w2h((pb - 160) * 256 + t, W2_h, b2_h, W2B_h);
        else if (pb < 166) dev_pack_w2o((pb - 164) * 256 + t, W2_o, b2_o, W2B_o);
        else if (pb < 182) dev_pack_sel((pb - 166) * 256 + t, SelB);
        else {
            int i = (pb - 182) * 256 + t;
            if (i < C_MSG * 4) Wm1T_d[i] = Wm1_d[(i & 3) * C_MSG + (i >> 2)];
        }
    } else {                                         // node term, layer d
        int n = (b - 3311) * 256 + t;
        if (n < N_NODES) {
            float xv = features[n];
            for (int o = 0; o < 30; ++o)
                bufA[n * 30 + o] = fmaf(xv, W1_d[o], b1_d[o]);
        }
    }
}

// Parallel scan over counts
__global__ __launch_bounds__(256) void scan_kernel(const int* __restrict__ counts,
                                                   int* __restrict__ offsets,
                                                   int* __restrict__ cursor) {
    __shared__ int ws[4];
    const int b = blockIdx.x, t = threadIdx.x;
    const int lane = t & 63, wv = t >> 6;
    int acc = 0;
    for (int i = t; i < b * 256; i += 256) acc += counts[i];
#pragma unroll
    for (int d = 32; d > 0; d >>= 1) acc += __shfl_xor(acc, d);
    if (lane == 0) ws[wv] = acc;
    __syncthreads();
    int base = ws[0] + ws[1] + ws[2] + ws[3];
    __syncthreads();
    int i = b * 256 + t;
    int v = (i < N_NODES) ? counts[i] : 0;
    int inc = v;
#pragma unroll
    for (int d = 1; d < 64; d <<= 1) {
        int u = __shfl_up(inc, d);
        if (lane >= d) inc += u;
    }
    if (lane == 63) ws[wv] = inc;
    __syncthreads();
    int waveoff = 0;
    for (int k = 0; k < wv; ++k) waveoff += ws[k];
    int excl = base + waveoff + inc - v;
    if (i < N_NODES) { offsets[i] = excl; cursor[i] = excl; }
    if (i == N_NODES - 1) offsets[N_NODES] = excl + v;
}

// scatter: ONE int4 stream {src, dst, ewbf, perm} in perm order
__global__ __launch_bounds__(256) void scatter_kernel(
    const int* __restrict__ src, const int* __restrict__ dst,
    const float* __restrict__ ew, int* __restrict__ cursor,
    int4* __restrict__ edata) {
    int e = blockIdx.x * 256 + threadIdx.x;
    if (e < N_EDGES) {
        int d = dst[e];
        int p = atomicAdd(&cursor[d], 1);
        edata[p] = make_int4(src[e], d, (int)pk_bf16(ew[2 * e], ew[2 * e + 1]), e);
    }
}

// ===========================================================================
// Layer-d edge kernel (CIN=1): full-fp32 VALU path, perm order
// ===========================================================================
__global__ __launch_bounds__(256) void edge_d_kernel(
    const float* __restrict__ x, const int4* __restrict__ edata,
    const float* __restrict__ ew,
    const float* __restrict__ Wm1T, const float* __restrict__ bm1,
    const float* __restrict__ Wm2, const float* __restrict__ bm2,
    const float* __restrict__ W2, const float* __restrict__ b2, bf16* __restrict__ msg)
{
    int t = blockIdx.x * 256 + threadIdx.x;
    int4 ed = edata[t];
    float xi = x[ed.y], xj = x[ed.x];
    int p = ed.w;
    float e0 = ew[2 * p], e1 = ew[2 * p + 1];
    float m = bm2[0];
    for (int j = 0; j < C_MSG; ++j) {
        const float* __restrict__ wr = Wm1T + j * 4;
        float h = bm1[j];
        h = fmaf(xi, wr[0], h);
        h = fmaf(xj, wr[1], h);
        h = fmaf(e0, wr[2], h);
        h = fmaf(e1, wr[3], h);
        h = fmaxf(h, 0.f);
        m = fmaf(h, Wm2[j], m);
    }
    float md = m * (xi - xj);
    for (int o = 0; o < 15; ++o) {
        float f0 = fmaf(md, W2[2 * o], b2[2 * o]);
        float f1 = fmaf(md, W2[2 * o + 1], b2[2 * o + 1]);
        *(unsigned int*)(msg + (size_t)t * 32 + 2 * o) = pk_bf16(f0, f1);
    }
}

// ===========================================================================
// MFMA edge kernel v3: block-cooperative GEMM1.
// Block = 4 waves, 64 edges; tmp[64][136] | h[64][232] | md[64][40] shared
// (52224 B -> 3 blocks/CU). Each wave gathers its 16 edges + computes its
// sel-diff (wave-local, pre-barrier). Barrier#1. GEMM1 split by N-pairs:
// w0:{0,4} w1:{1,5} w2:{2}+tile12 w3:{3}; each wave computes its columns for
// ALL 64 edges -> GEMM1 B-frag loads 104->26 per block (same MFMA set ->
// bit-identical h). Barrier#2. GEMM2/GEMM3 wave-local on own 16 rows (diff
// regs match C-layout). Biases folded via constant-1 cols (tmp30/h200/md30).
// ===========================================================================
template<int COUT>
__global__ __launch_bounds__(256) void edge_mfma(
    const bf16* __restrict__ xbf, const bf16* __restrict__ xlo,
    const int4* __restrict__ edata,
    const bf16* __restrict__ Wm1B, const bf16* __restrict__ SelB,
    const bf16* __restrict__ Wm2B, const bf16* __restrict__ W2B,
    bf16* __restrict__ msg)
{
    __shared__ __align__(16) char smem_all[52224];
    const int tid = threadIdx.x, w = tid >> 6, lane = tid & 63;
    bf16* tmpp = (bf16*)smem_all;                 // [64][136]
    bf16* hp   = (bf16*)(smem_all + 17408);       // [64][232]
    bf16* mdp  = (bf16*)(smem_all + 47104);       // [64][40]

    const int col = lane & 15, quad = lane >> 4, row0 = quad * 4;
    const int myrow = w * 16;                     // this wave's edge rows
    const int ebase = blockIdx.x * 64 + myrow;

    // h pad cols [200,224) of OWN rows: col200=1 (bm2 slot), rest 0
    for (int i = lane; i < 16 * 24; i += 64) {
        int r = myrow + i / 24, c = 200 + i % 24;
        hp[r * 232 + c] = (c == 200) ? (bf16)1.f : (bf16)0.f;
    }

    // ---- gather own 16 edges: s0 hi_d, s1 hi_s, s2 lo_d, s3 lo_s ----
    {
        int r = lane >> 2, s = lane & 3;
        int4 ed = edata[ebase + r];
        int id = (s & 1) ? ed.x : ed.y;           // s odd -> src, even -> dst
        const bf16* sp = (((s >> 1) == 0) ? xbf : xlo) + (size_t)id * 32;
        bf16x8 v0 = *(const bf16x8*)(sp);
        bf16x8 v1 = *(const bf16x8*)(sp + 8);
        bf16x8 v2 = *(const bf16x8*)(sp + 16);
        bf16x8 v3 = *(const bf16x8*)(sp + 24);
        bf16* dp = tmpp + (size_t)(myrow + r) * 136 + s * 32;
        *(bf16x8*)(dp) = v0;
        *(bf16x8*)(dp + 8) = v1;
        *(bf16x8*)(dp + 16) = v2;
        *(bf16x8*)(dp + 24) = v3;
        if (lane < 16) {
            int4 e2 = edata[ebase + lane];
            *(unsigned int*)(tmpp + (size_t)(myrow + lane) * 136 + 62) =
                (unsigned int)e2.z;               // ew cols 62,63
        }
    }

    // ---- own A-frags + selector diff (wave-local, pre-barrier) ----
    bf16x8 A0[4], A1[4];
    f32x4 dc0 = {0.f, 0.f, 0.f, 0.f}, dc1 = {0.f, 0.f, 0.f, 0.f};
    {
        const bf16* tp = tmpp + (size_t)(myrow + col) * 136;
        A0[0] = A0[1] = A0[2] = A0[3] = *(const bf16x8*)(tp + quad * 8);
        A1[0] = A1[1] = A1[2] = A1[3] = *(const bf16x8*)(tp + 32 + quad * 8);
        bf16x8 a2 = *(const bf16x8*)(tp + 64 + quad * 8);
        bf16x8 a3 = *(const bf16x8*)(tp + 96 + quad * 8);
        bf16x8 b;
        b = *(const bf16x8*)(SelB + (size_t)0 * 512 + lane * 8);
        dc0 = __builtin_amdgcn_mfma_f32_16x16x32_bf16(A0[0], b, dc0, 0, 0, 0);
        b = *(const bf16x8*)(SelB + (size_t)1 * 512 + lane * 8);
        dc1 = __builtin_amdgcn_mfma_f32_16x16x32_bf16(A0[0], b, dc1, 0, 0, 0);
        b = *(const bf16x8*)(SelB + (size_t)2 * 512 + lane * 8);
        dc0 = __builtin_amdgcn_mfma_f32_16x16x32_bf16(A1[0], b, dc0, 0, 0, 0);
        b = *(const bf16x8*)(SelB + (size_t)3 * 512 + lane * 8);
        dc1 = __builtin_amdgcn_mfma_f32_16x16x32_bf16(A1[0], b, dc1, 0, 0, 0);
        b = *(const bf16x8*)(SelB + (size_t)4 * 512 + lane * 8);
        dc0 = __builtin_amdgcn_mfma_f32_16x16x32_bf16(a2, b, dc0, 0, 0, 0);
        b = *(const bf16x8*)(SelB + (size_t)5 * 512 + lane * 8);
        dc1 = __builtin_amdgcn_mfma_f32_16x16x32_bf16(a2, b, dc1, 0, 0, 0);
        b = *(const bf16x8*)(SelB + (size_t)6 * 512 + lane * 8);
        dc0 = __builtin_amdgcn_mfma_f32_16x16x32_bf16(a3, b, dc0, 0, 0, 0);
        b = *(const bf16x8*)(SelB + (size_t)7 * 512 + lane * 8);
        dc1 = __builtin_amdgcn_mfma_f32_16x16x32_bf16(a3, b, dc1, 0, 0, 0);
    }

    __syncthreads();   // tmp complete block-wide

    // fill A-frags of the other 3 tiles (branch is wave-uniform)
#pragma unroll
    for (int t = 0; t < 4; ++t) {
        if (t != w) {
            const bf16* tp = tmpp + (size_t)(t * 16 + col) * 136;
            A0[t] = *(const bf16x8*)(tp + quad * 8);
            A1[t] = *(const bf16x8*)(tp + 32 + quad * 8);
        }
    }

    // ---- GEMM1 (N-split): this wave's pairs, all 4 A-tiles ----
    const int npair = (w < 2) ? 2 : 1;
#pragma unroll
    for (int i = 0; i < 2; ++i) {
        if (i < npair) {
            int p = (i == 0) ? w : (w + 4);
            const bf16* Wf = Wm1B + (size_t)(4 * p) * 512 + lane * 8;
            bf16x8 be0 = *(const bf16x8*)(Wf);
            bf16x8 be1 = *(const bf16x8*)(Wf + 512);
            bf16x8 bo0 = *(const bf16x8*)(Wf + 1024);
            bf16x8 bo1 = *(const bf16x8*)(Wf + 1536);
#pragma unroll
            for (int t = 0; t < 4; ++t) {
                f32x4 ae = {0.f, 0.f, 0.f, 0.f}, ao = {0.f, 0.f, 0.f, 0.f};
                ae = __builtin_amdgcn_mfma_f32_16x16x32_bf16(A0[t], be0, ae, 0, 0, 0);
                ae = __builtin_amdgcn_mfma_f32_16x16x32_bf16(A1[t], be1, ae, 0, 0, 0);
                ao = __builtin_amdgcn_mfma_f32_16x16x32_bf16(A0[t], bo0, ao, 0, 0, 0);
                ao = __builtin_amdgcn_mfma_f32_16x16x32_bf16(A1[t], bo1, ao, 0, 0, 0);
#pragma unroll
                for (int rg = 0; rg < 4; ++rg) {
                    unsigned int u = pk_bf16(fmaxf(ae[rg], 0.f), fmaxf(ao[rg], 0.f));
                    *(unsigned int*)(hp + (size_t)(t * 16 + row0 + rg) * 232 +
                                     p * 32 + 2 * col) = u;
                }
            }
        }
    }
    if (w == 2) {   // leftover N-tile 12: cols 192..199 real
        const bf16* Wf = Wm1B + (size_t)24 * 512 + lane * 8;
        bf16x8 b0 = *(const bf16x8*)(Wf);
        bf16x8 b1 = *(const bf16x8*)(Wf + 512);
#pragma unroll
        for (int t = 0; t < 4; ++t) {
            f32x4 acc = {0.f, 0.f, 0.f, 0.f};
            acc = __builtin_amdgcn_mfma_f32_16x16x32_bf16(A0[t], b0, acc, 0, 0, 0);
            acc = __builtin_amdgcn_mfma_f32_16x16x32_bf16(A1[t], b1, acc, 0, 0, 0);
            if (col < 8) {
#pragma unroll
                for (int rg = 0; rg < 4; ++rg)
                    hp[(size_t)(t * 16 + row0 + rg) * 232 + 192 + col] =
                        (bf16)fmaxf(acc[rg], 0.f);
            }
        }
    }

    __syncthreads();   // h complete block-wide

    // ---- GEMM2 on OWN 16 edges: h[16x224] @ Wm2[224x32]; md = m*diff ----
    f32x4 m0 = {0.f, 0.f, 0.f, 0.f}, m1 = {0.f, 0.f, 0.f, 0.f};
#pragma unroll
    for (int kt = 0; kt < 7; ++kt) {
        bf16x8 a = *(const bf16x8*)(hp + (size_t)(myrow + col) * 232 + kt * 32 + quad * 8);
        bf16x8 b0 = *(const bf16x8*)(Wm2B + (size_t)kt * 512 + lane * 8);
        bf16x8 b1 = *(const bf16x8*)(Wm2B + (size_t)(7 + kt) * 512 + lane * 8);
        m0 = __builtin_amdgcn_mfma_f32_16x16x32_bf16(a, b0, m0, 0, 0, 0);
        m1 = __builtin_amdgcn_mfma_f32_16x16x32_bf16(a, b1, m1, 0, 0, 0);
    }
#pragma unroll
    for (int rg = 0; rg < 4; ++rg) {
        unsigned int u = (col == 15) ? pk_bf16(1.f, 0.f)
                                     : pk_bf16(m0[rg] * dc0[rg], m1[rg] * dc1[rg]);
        *(unsigned int*)(mdp + (size_t)(myrow + row0 + rg) * 40 + 2 * col) = u;
    }

    // ---- GEMM3: md[16x32] @ W2[32xN] -> msg (wave-local) ----
    bf16x8 am = *(const bf16x8*)(mdp + (size_t)(myrow + col) * 40 + quad * 8);
    if (COUT == 30) {
        bf16x8 b0 = *(const bf16x8*)(W2B + lane * 8);
        bf16x8 b1 = *(const bf16x8*)(W2B + 512 + lane * 8);
        f32x4 c0 = {0.f, 0.f, 0.f, 0.f}, c1 = {0.f, 0.f, 0.f, 0.f};
        c0 = __builtin_amdgcn_mfma_f32_16x16x32_bf16(am, b0, c0, 0, 0, 0);
        c1 = __builtin_amdgcn_mfma_f32_16x16x32_bf16(am, b1, c1, 0, 0, 0);
#pragma unroll
        for (int rg = 0; rg < 4; ++rg)
            *(unsigned int*)(msg + (size_t)(ebase + row0 + rg) * 32 + 2 * col) =
                pk_bf16(c0[rg], c1[rg]);
    } else {
        bf16x8 b0 = *(const bf16x8*)(W2B + lane * 8);
        f32x4 c0 = {0.f, 0.f, 0.f, 0.f};
        c0 = __builtin_amdgcn_mfma_f32_16x16x32_bf16(am, b0, c0, 0, 0, 0);
        if (col == 0) {
#pragma unroll
            for (int rg = 0; rg < 4; ++rg)
                msg[(size_t)(ebase + row0 + rg) * 32] = (bf16)c0[rg];
        }
    }
}

// ===========================================================================
// Fused aggregation + next node term. Half-wave per node. msg loop unrolled
// x4 (batch loads; accumulation ORDER preserved -> numerically identical).
// ===========================================================================
template<int CNEXT>
__global__ __launch_bounds__(256) void agg_fused(
    const bf16* __restrict__ msg, const int* __restrict__ offsets,
    const float* __restrict__ bufc,
    const float* __restrict__ W1n, const float* __restrict__ b1n,
    float* __restrict__ bufn,
    bf16* __restrict__ xbf, bf16* __restrict__ xlo) {
    int gh = (blockIdx.x * 256 + threadIdx.x) >> 5;
    int lane = threadIdx.x & 31;
    int s0 = offsets[gh], s1 = offsets[gh + 1];
    float r0 = 0.f, r1 = 0.f;
    if (lane < 15) {
        float v0 = 0.f, v1 = 0.f;
        const unsigned int* mp =
            (const unsigned int*)(msg + (size_t)s0 * 32 + lane * 2);
        int cnt = s1 - s0, j = 0;
        for (; j + 4 <= cnt; j += 4) {
            unsigned int u0 = mp[(size_t)(j + 0) * 16];
            unsigned int u1 = mp[(size_t)(j + 1) * 16];
            unsigned int u2 = mp[(size_t)(j + 2) * 16];
            unsigned int u3 = mp[(size_t)(j + 3) * 16];
            union { unsigned int u; bf16 b[2]; } c0, c1, c2, c3;
            c0.u = u0; c1.u = u1; c2.u = u2; c3.u = u3;
            v0 += (float)c0.b[0]; v1 += (float)c0.b[1];
            v0 += (float)c1.b[0]; v1 += (float)c1.b[1];
            v0 += (float)c2.b[0]; v1 += (float)c2.b[1];
            v0 += (float)c3.b[0]; v1 += (float)c3.b[1];
        }
        for (; j < cnt; ++j) {
            union { unsigned int u; bf16 b[2]; } cv;
            cv.u = mp[(size_t)j * 16];
            v0 += (float)cv.b[0]; v1 += (float)cv.b[1];
        }
        float f0 = bufc[(size_t)gh * 30 + 2 * lane] + v0;
        float f1 = bufc[(size_t)gh * 30 + 2 * lane + 1] + v1;
        r0 = fmaxf(f0, 0.f);
        r1 = fmaxf(f1, 0.f);
        bf16 h0 = (bf16)r0, h1 = (bf16)r1;
        union { bf16 h[2]; unsigned int u; } hi;
        hi.h[0] = h0; hi.h[1] = h1;
        *(unsigned int*)(xbf + (size_t)gh * 32 + 2 * lane) = hi.u;
        *(unsigned int*)(xlo + (size_t)gh * 32 + 2 * lane) =
            pk_bf16(r0 - (float)h0, r1 - (float)h1);
    } else if (lane == 15) {
        *(unsigned int*)(xbf + (size_t)gh * 32 + 30) = pk_bf16(1.f, 0.f);
        *(unsigned int*)(xlo + (size_t)gh * 32 + 30) = 0u;
    }
    // ---- next node term (fma order == original node_kernel) ----
    if (CNEXT == 30) {
        float acc0 = 0.f, acc1 = 0.f;
        if (lane < 15) { acc0 = b1n[2 * lane]; acc1 = b1n[2 * lane + 1]; }
        for (int k2 = 0; k2 < 15; ++k2) {
            float rk0 = __shfl(r0, k2, 32);
            float rk1 = __shfl(r1, k2, 32);
            if (lane < 15) {
                const float* w0 = W1n + (2 * k2) * 30 + 2 * lane;
                const float* w1 = W1n + (2 * k2 + 1) * 30 + 2 * lane;
                acc0 = fmaf(rk0, w0[0], acc0);
                acc1 = fmaf(rk0, w0[1], acc1);
                acc0 = fmaf(rk1, w1[0], acc0);
                acc1 = fmaf(rk1, w1[1], acc1);
            }
        }
        if (lane < 15) {
            bufn[(size_t)gh * 30 + 2 * lane] = acc0;
            bufn[(size_t)gh * 30 + 2 * lane + 1] = acc1;
        }
    } else {
        float acc = b1n[0];
        for (int k2 = 0; k2 < 15; ++k2) {
            float rk0 = __shfl(r0, k2, 32);
            float rk1 = __shfl(r1, k2, 32);
            acc = fmaf(rk0, W1n[2 * k2], acc);
            acc = fmaf(rk1, W1n[2 * k2 + 1], acc);
        }
        if (lane == 0) bufn[gh] = acc;
    }
}

// Final aggregation (msg COUT=1): out[gh] += msgsum
__global__ __launch_bounds__(256) void agg_last(const bf16* __restrict__ msg,
                                                const int* __restrict__ offsets,
                                                float* __restrict__ out) {
    int gh = (blockIdx.x * 256 + threadIdx.x) >> 5;
    int lane = threadIdx.x & 31;
    int s0 = offsets[gh], s1 = offsets[gh + 1];
    float v = 0.f;
    for (int j = s0 + lane; j < s1; j += 32) v += (float)msg[(size_t)j * 32];
#pragma unroll
    for (int o = 16; o > 0; o >>= 1) v += __shfl_xor(v, o);
    if (lane == 0) out[gh] += v;
}

// ===========================================================================
extern "C" void kernel_launch(void* const* d_in, const int* in_sizes, int n_in,
                              void* d_out, int out_size, void* d_ws, size_t ws_size,
                              hipStream_t stream) {
    const float* features = (const float*)d_in[0];
    const int*   edges    = (const int*)d_in[1];
    const float* ew       = (const float*)d_in[2];

    const float* W1_d  = (const float*)d_in[3];
    const float* b1_d  = (const float*)d_in[4];
    const float* Wm1_d = (const float*)d_in[5];
    const float* bm1_d = (const float*)d_in[6];
    const float* Wm2_d = (const float*)d_in[7];
    const float* bm2_d = (const float*)d_in[8];
    const float* W2_d  = (const float*)d_in[9];
    const float* b2_d  = (const float*)d_in[10];

    const float* W1_h  = (const float*)d_in[11];
    const float* b1_h  = (const float*)d_in[12];
    const float* Wm1_h = (const float*)d_in[13];
    const float* bm1_h = (const float*)d_in[14];
    const float* Wm2_h = (const float*)d_in[15];
    const float* bm2_h = (const float*)d_in[16];
    const float* W2_h  = (const float*)d_in[17];
    const float* b2_h  = (const float*)d_in[18];

    const float* W1_o  = (const float*)d_in[19];
    const float* b1_o  = (const float*)d_in[20];
    const float* Wm1_o = (const float*)d_in[21];
    const float* bm1_o = (const float*)d_in[22];
    const float* Wm2_o = (const float*)d_in[23];
    const float* bm2_o = (const float*)d_in[24];
    const float* W2_o  = (const float*)d_in[25];
    const float* b2_o  = (const float*)d_in[26];

    const int* src = edges;
    const int* dst = edges + N_EDGES;
    float* out = (float*)d_out;

    // ---- workspace carve-up ----
    char* p = (char*)d_ws;
    auto alloc = [&](size_t bytes) { char* r = p; p += (bytes + 63) & ~(size_t)63; return r; };
    float* bufA    = (float*)alloc((size_t)N_NODES * 30 * 4);
    float* bufB    = (float*)alloc((size_t)N_NODES * 30 * 4);
    bf16*  msg     = (bf16*) alloc((size_t)N_EDGES * 32 * 2);
    bf16*  xbf     = (bf16*) alloc((size_t)N_NODES * 32 * 2);
    bf16*  xlo     = (bf16*) alloc((size_t)N_NODES * 32 * 2);
    int*   counts  = (int*)  alloc((size_t)N_NODES * 4);
    int*   offsets = (int*)  alloc((size_t)(N_NODES + 1) * 4);
    int*   cursor  = (int*)  alloc((size_t)N_NODES * 4);
    int4*  edata   = (int4*) alloc((size_t)N_EDGES * 16);
    float* Wm1T_d  = (float*)alloc((size_t)C_MSG * 4 * 4);
    bf16*  Wm1B_h  = (bf16*) alloc((size_t)26 * 512 * 2);
    bf16*  Wm1B_o  = (bf16*) alloc((size_t)26 * 512 * 2);
    bf16*  Wm2B_h  = (bf16*) alloc((size_t)14 * 512 * 2);
    bf16*  Wm2B_o  = (bf16*) alloc((size_t)14 * 512 * 2);
    bf16*  W2B_h   = (bf16*) alloc((size_t)2 * 512 * 2);
    bf16*  W2B_o   = (bf16*) alloc((size_t)1 * 512 * 2);
    bf16*  SelB    = (bf16*) alloc((size_t)8 * 512 * 2);

    // ---- setup ----
    hipMemsetAsync(counts, 0, (size_t)N_NODES * 4, stream);
    setup_a<<<3507, 256, 0, stream>>>(dst, counts,
        Wm1_h, bm1_h, Wm1_o, bm1_o, Wm2_h, bm2_h, Wm2_o, bm2_o,
        W2_h, b2_h, W2_o, b2_o, Wm1_d,
        Wm1B_h, Wm1B_o, Wm2B_h, Wm2B_o, W2B_h, W2B_o, SelB, Wm1T_d,
        features, W1_d, b1_d, bufA);
    scan_kernel<<<(N_NODES + 255) / 256, 256, 0, stream>>>(counts, offsets, cursor);
    scatter_kernel<<<N_EDGES / 256, 256, 0, stream>>>(src, dst, ew, cursor, edata);

    dim3 tb(256);
    dim3 eb_mfma(N_EDGES / 64);
    dim3 eb_valu(N_EDGES / 256);
    dim3 ab(N_NODES * 32 / 256);

    // ---- layer d ----
    edge_d_kernel<<<eb_valu, tb, 0, stream>>>(features, edata, ew,
        Wm1T_d, bm1_d, Wm2_d, bm2_d, W2_d, b2_d, msg);
    agg_fused<30><<<ab, tb, 0, stream>>>(msg, offsets, bufA, W1_h, b1_h, bufB, xbf, xlo);

    // ---- h1 ----
    edge_mfma<30><<<eb_mfma, tb, 0, stream>>>(xbf, xlo, edata,
        Wm1B_h, SelB, Wm2B_h, W2B_h, msg);
    agg_fused<30><<<ab, tb, 0, stream>>>(msg, offsets, bufB, W1_h, b1_h, bufA, xbf, xlo);

    // ---- h2 ----
    edge_mfma<30><<<eb_mfma, tb, 0, stream>>>(xbf, xlo, edata,
        Wm1B_h, SelB, Wm2B_h, W2B_h, msg);
    agg_fused<30><<<ab, tb, 0, stream>>>(msg, offsets, bufA, W1_h, b1_h, bufB, xbf, xlo);

    // ---- h3 (next node term = output layer -> writes d_out) ----
    edge_mfma<30><<<eb_mfma, tb, 0, stream>>>(xbf, xlo, edata,
        Wm1B_h, SelB, Wm2B_h, W2B_h, msg);
    agg_fused<1><<<ab, tb, 0, stream>>>(msg, offsets, bufB, W1_o, b1_o, out, xbf, xlo);

    // ---- output layer ----
    edge_mfma<1><<<eb_mfma, tb, 0, stream>>>(xbf, xlo, edata,
        Wm1B_o, SelB, Wm2B_o, W2B_o, msg);
    agg_last<<<ab, tb, 0, stream>>>(msg, offsets, out);
}